// Round 2
// baseline (735.062 us; speedup 1.0000x reference)
//
#include <hip/hip_runtime.h>
#include <stdint.h>

typedef unsigned short u16;
typedef __attribute__((ext_vector_type(2))) unsigned short u16x2;
typedef __attribute__((ext_vector_type(4))) unsigned short u16x4;
typedef __attribute__((ext_vector_type(8))) short s16x8;   // 8 bf16 (MFMA A/B frag)
typedef __attribute__((ext_vector_type(2))) float f32x2;
typedef __attribute__((ext_vector_type(4))) float f32x4;   // MFMA C/D frag

#define NROWS 100000
#define RPB   16
#define NBLK  (NROWS / RPB)   // 6250 exact

// LDS pitches (elements)
#define PF  488   // fin  (bf16) channel-major [s0 128 | s1 k*64+i | s2 k*32+i]
#define PS  360   // scb  (bf16) mlp_in = [scalar_in 128 | inv 224]
#define PH  136   // hb   (bf16) silu hidden 128
#define PD  232   // dotb (bf16) dot 224
#define PUV 972   // uv   (f32)  [U 0..479 | V 480..959]
#define PA  484   // aout (f32)  mlp_out 480
#define PI  132   // inner(f32)  128

// packed-weight bases (elements) in d_ws (always bf16 after pack)
#define B_UW0 0
#define B_UW1 16384
#define B_UW2 20480
#define B_VW0 21504
#define B_VW1 37888
#define B_VW2 41984
#define B_DW  43008
#define B_W1  71680
#define B_W2  116736
#define PACK_TOT 178176

__device__ inline float bf2f(u16 u) {
    union { uint32_t i; float f; } v; v.i = (uint32_t)u << 16; return v.f;
}
__device__ inline u16 f2bf(float f) {  // round-to-nearest-even
    union { float f; uint32_t i; } v; v.f = f;
    return (u16)((v.i + 0x7fffu + ((v.i >> 16) & 1u)) >> 16);
}
__device__ inline float wsum32(float v) {  // sum within each 32-lane half
    #pragma unroll
    for (int m = 16; m >= 1; m >>= 1) v += __shfl_xor(v, m);
    return v;
}
// dtype probe: bf16 N(0,1) data never exceeds 1e10; f32 data read as bf16 pairs
// has random-mantissa "bf16"s that blow past it with p~0.37/lane.
__device__ inline bool detect_f32(const void* xs) {
    const u16 v = ((const u16*)xs)[threadIdx.x & 63];
    const float f = bf2f(v);
    return __any(!(fabsf(f) < 1e10f)) != 0;
}
__device__ inline float ldin(const void* p, size_t i, bool f32) {
    return f32 ? ((const float*)p)[i] : bf2f(((const u16*)p)[i]);
}

struct Ptrs {
    const void *xs, *xp, *lng, *lnb, *o3w, *o3b;
    const void *Uw0, *Uw1, *Uw2, *Ub0, *Vw0, *Vw1, *Vw2, *Vb0;
    const void *dw, *w1, *b1, *w2, *b2;
    const u16 *ws;
    void *out;
};

// One 16x16 output tile, K = KS*32, bf16 MFMA.
// A: LDS row-major bf16; B: packed frags (ws, bf16) or raw row-major global (dtype wf32).
// TYPE 0: outF[row*outPitch + o] = acc*scale + bias[o]   (bias: LDS f32 or null)
// TYPE 1: outH[row*PH + o] = bf16( silu(acc + bias[o]) )
template<int KS, bool PACKED, int TYPE>
__device__ inline void mm_tile(const u16* A, int pitchA, const void* W, int D,
                               int tile, int lane, float scale, const float* bias,
                               float* outF, int outPitch, u16* outH, bool wf32)
{
    f32x4 acc = {0.f, 0.f, 0.f, 0.f};
    const int r = lane & 15, g = lane >> 4;
    const u16* arow = A + r * pitchA + g * 8;
    #pragma unroll
    for (int ks = 0; ks < KS; ++ks) {
        s16x8 a = *(const s16x8*)(arow + ks * 32);
        s16x8 b;
        if (PACKED) {
            b = *(const s16x8*)((const u16*)W + (((size_t)tile * KS + ks) * 64 + (size_t)lane) * 8);
        } else {
            union { u16 u[8]; s16x8 v; } bb;
            const int k0 = ks * 32 + g * 8, o = tile * 16 + r;
            #pragma unroll
            for (int j = 0; j < 8; ++j) {
                const size_t idx = (size_t)(k0 + j) * D + o;
                bb.u[j] = wf32 ? f2bf(((const float*)W)[idx]) : ((const u16*)W)[idx];
            }
            b = bb.v;
        }
        acc = __builtin_amdgcn_mfma_f32_16x16x32_bf16(a, b, acc, 0, 0, 0);
    }
    const int o = tile * 16 + r;
    if (TYPE == 0) {
        const float bv = bias ? bias[o] : 0.f;
        #pragma unroll
        for (int q = 0; q < 4; ++q)
            outF[(size_t)(g * 4 + q) * outPitch + o] = acc[q] * scale + bv;
    } else {
        const float bv = bias[o];
        #pragma unroll
        for (int q = 0; q < 4; ++q) {
            float x = acc[q] + bv;
            outH[(g * 4 + q) * PH + o] = f2bf(x / (1.f + expf(-x)));
        }
    }
}

__global__ void pack_weights(Ptrs P, u16* ws)
{
    const bool wf32 = detect_f32(P.xs);
    const int gid = blockIdx.x * 256 + threadIdx.x;
    if (gid >= PACK_TOT) return;
    const int  base[10] = {B_UW0, B_UW1, B_UW2, B_VW0, B_VW1, B_VW2, B_DW, B_W1, B_W2, PACK_TOT};
    const int  Kd[9]    = {128, 64, 32, 128, 64, 32, 224, 352, 128};
    const int  Dd[9]    = {128, 64, 32, 128, 64, 32, 128, 352, 480};
    const void* srcs[9] = {P.Uw0, P.Uw1, P.Uw2, P.Vw0, P.Vw1, P.Vw2, P.dw, P.w1, P.w2};
    // (Dd[7] is unused for W1 stride math below; strides come from Dd[] uniformly)
    const int  Dstride[9] = {128, 64, 32, 128, 64, 32, 128, 128, 480};
    int m = 0;
    for (int i = 1; i < 9; ++i) if (gid >= base[i]) m = i;
    (void)Kd; (void)Dd;
    const int e = gid - base[m];
    const int j = e & 7, lane = (e >> 3) & 63, tk = e >> 9;
    const int Ks = Kd[m] >> 5;
    const int ks = tk % Ks, tile = tk / Ks;
    const int k = ks * 32 + ((lane >> 4) << 3) + j;
    const int o = tile * 16 + (lane & 15);
    const size_t idx = (size_t)k * Dstride[m] + o;
    ws[gid] = wf32 ? f2bf(((const float*)srcs[m])[idx]) : ((const u16*)srcs[m])[idx];
}

// ---------------- stage 1: scalar LN + O3 layernorm, templated on input dtype ----------------
template<int DT>
__device__ inline void stage1_core(const Ptrs& P, u16* fin, u16* scb, int tid, int row0)
{
    const int hw = tid >> 5, l32 = tid & 31;
    for (int rr = hw; rr < RPB; rr += 8) {
        const size_t row = (size_t)(row0 + rr);
        const u16*   xsb = (const u16*)P.xs + row * 128;
        const float* xsf = (const float*)P.xs + row * 128;
        const u16*   xpb = (const u16*)P.xp + row * 480;
        const float* xpf = (const float*)P.xp + row * 480;
        {   // scalar layernorm -> scb[rr][0..127]
            float v[4];
            if (DT) { f32x4 u = *(const f32x4*)(xsf + l32 * 4); v[0]=u[0];v[1]=u[1];v[2]=u[2];v[3]=u[3]; }
            else    { u16x4 u = *(const u16x4*)(xsb + l32 * 4);
                      v[0]=bf2f(u[0]);v[1]=bf2f(u[1]);v[2]=bf2f(u[2]);v[3]=bf2f(u[3]); }
            float s  = v[0] + v[1] + v[2] + v[3];
            float s2 = v[0]*v[0] + v[1]*v[1] + v[2]*v[2] + v[3]*v[3];
            s = wsum32(s); s2 = wsum32(s2);
            const float mu = s * (1.f / 128.f);
            const float rs = 1.f / sqrtf(s2 * (1.f / 128.f) - mu * mu + 1e-5f);
            const int c = l32 * 4;
            #pragma unroll
            for (int j2 = 0; j2 < 4; ++j2)
                scb[rr * PS + c + j2] =
                    f2bf((v[j2] - mu) * rs * ldin(P.lng, c + j2, DT) + ldin(P.lnb, c + j2, DT));
        }
        {   // s0 O3-LN -> fin[rr][0..127]
            float v[4];
            if (DT) { f32x4 u = *(const f32x4*)(xpf + l32 * 4); v[0]=u[0];v[1]=u[1];v[2]=u[2];v[3]=u[3]; }
            else    { u16x4 u = *(const u16x4*)(xpb + l32 * 4);
                      v[0]=bf2f(u[0]);v[1]=bf2f(u[1]);v[2]=bf2f(u[2]);v[3]=bf2f(u[3]); }
            float s  = v[0] + v[1] + v[2] + v[3];
            float s2 = v[0]*v[0] + v[1]*v[1] + v[2]*v[2] + v[3]*v[3];
            s = wsum32(s); s2 = wsum32(s2);
            const float mu = s * (1.f / 128.f);
            const float rs = 1.f / sqrtf(s2 * (1.f / 128.f) - mu * mu + 1e-5f);
            const int c = l32 * 4;
            #pragma unroll
            for (int j2 = 0; j2 < 4; ++j2)
                fin[rr * PF + c + j2] =
                    f2bf((v[j2] - mu) * rs * ldin(P.o3w, c + j2, DT) + ldin(P.o3b, c + j2, DT));
        }
        {   // s1 (64 irreps x 3) -> fin[rr][128 + k*64 + i]
            const int cb = l32 * 6;
            float w[6];
            if (DT) {
                f32x2 a0 = *(const f32x2*)(xpf + 128 + cb);
                f32x2 a1 = *(const f32x2*)(xpf + 128 + cb + 2);
                f32x2 a2 = *(const f32x2*)(xpf + 128 + cb + 4);
                w[0]=a0[0]; w[1]=a0[1]; w[2]=a1[0]; w[3]=a1[1]; w[4]=a2[0]; w[5]=a2[1];
            } else {
                u16x2 a0 = *(const u16x2*)(xpb + 128 + cb);
                u16x2 a1 = *(const u16x2*)(xpb + 128 + cb + 2);
                u16x2 a2 = *(const u16x2*)(xpb + 128 + cb + 4);
                w[0]=bf2f(a0[0]); w[1]=bf2f(a0[1]); w[2]=bf2f(a1[0]);
                w[3]=bf2f(a1[1]); w[4]=bf2f(a2[0]); w[5]=bf2f(a2[1]);
            }
            float ss = 0.f;
            #pragma unroll
            for (int j2 = 0; j2 < 6; ++j2) ss += w[j2] * w[j2];
            ss = wsum32(ss);
            const float rs = 1.f / sqrtf(ss * (1.f / 192.f) + 1e-5f);
            #pragma unroll
            for (int j2 = 0; j2 < 6; ++j2) {
                const int c = cb + j2, i = c / 3, k = c - 3 * i;
                fin[rr * PF + 128 + k * 64 + i] = f2bf(w[j2] * rs * ldin(P.o3w, 128 + i, DT));
            }
        }
        {   // s2 (32 irreps x 5) -> fin[rr][320 + k*32 + i]
            const int cb = l32 * 5;
            float w[5];
            #pragma unroll
            for (int j2 = 0; j2 < 5; ++j2)
                w[j2] = DT ? xpf[320 + cb + j2] : bf2f(xpb[320 + cb + j2]);
            float ss = 0.f;
            #pragma unroll
            for (int j2 = 0; j2 < 5; ++j2) ss += w[j2] * w[j2];
            ss = wsum32(ss);
            const float rs = 1.f / sqrtf(ss * (1.f / 160.f) + 1e-5f);
            #pragma unroll
            for (int j2 = 0; j2 < 5; ++j2) {
                const int c = cb + j2, i = c / 5, k = c - 5 * i;
                fin[rr * PF + 320 + k * 32 + i] = f2bf(w[j2] * rs * ldin(P.o3w, 192 + i, DT));
            }
        }
    }
}

// ---------------- stage 7: outputs, templated on dtype ----------------
template<int DT>
__device__ inline void stage7_core(const Ptrs& P, const float* uv, const float* aout,
                                   const float* inner, int tid, int row0)
{
    for (int idx = tid; idx < RPB * 128; idx += 256) {
        const int r2 = idx >> 7, c = idx & 127;
        const size_t row = (size_t)(row0 + r2);
        const float xs = ldin(P.xs, row * 128 + c, DT);
        const float val = xs + aout[r2 * PA + 224 + c] * inner[r2 * PI + c]
                             + aout[r2 * PA + 352 + c];
        if (DT) ((float*)P.out)[row * 128 + c] = val;
        else    ((u16*)P.out)[row * 128 + c] = f2bf(val);
    }
    for (int idx = tid; idx < RPB * 480; idx += 256) {
        const int r2 = idx / 480, c = idx - r2 * 480;
        const size_t row = (size_t)(row0 + r2);
        float u, av;
        if (c < 128)      { u = uv[r2 * PUV + c];                av = aout[r2 * PA + c]; }
        else if (c < 320) { const int e = c - 128, i = e / 3, k = e - 3 * i;
                            u = uv[r2 * PUV + 128 + 64 * k + i]; av = aout[r2 * PA + 128 + i]; }
        else              { const int e = c - 320, i = e / 5, k = e - 5 * i;
                            u = uv[r2 * PUV + 320 + 32 * k + i]; av = aout[r2 * PA + 192 + i]; }
        const float val = ldin(P.xp, row * 480 + c, DT) + u * av;
        const size_t oi = (size_t)NROWS * 128 + row * 480 + c;
        if (DT) ((float*)P.out)[oi] = val;
        else    ((u16*)P.out)[oi] = f2bf(val);
    }
}

template<bool PACKED>
__global__ __launch_bounds__(256, 1) void xpainn_main(Ptrs P)
{
    __shared__ __align__(16) u16  fin[RPB * PF];
    __shared__ __align__(16) u16  scb[RPB * PS];
    __shared__ __align__(16) u16  hb[RPB * PH];
    __shared__ __align__(16) u16  dotb[RPB * PD];
    __shared__ __align__(16) float uv[RPB * PUV];
    __shared__ __align__(16) float aout[RPB * PA];
    __shared__ __align__(16) float inner[RPB * PI];
    __shared__ __align__(16) float bcom[864];   // [Ub0 | Vb0 | b1 | b2(480)]

    const int tid = threadIdx.x;
    const int lane = tid & 63, wave = tid >> 6;
    const int row0 = blockIdx.x * RPB;
    const bool isf32 = detect_f32(P.xs);

    // bias vectors -> LDS f32 (dtype-independent downstream)
    for (int i = tid; i < 864; i += 256) {
        const void* src; int off;
        if (i < 128)      { src = P.Ub0; off = i; }
        else if (i < 256) { src = P.Vb0; off = i - 128; }
        else if (i < 384) { src = P.b1;  off = i - 256; }
        else              { src = P.b2;  off = i - 384; }
        bcom[i] = ldin(src, off, isf32);
    }
    if (isf32) stage1_core<1>(P, fin, scb, tid, row0);
    else       stage1_core<0>(P, fin, scb, tid, row0);
    __syncthreads();

    // ---------------- stage 2: U,V O3-linears -> uv ----------------
    for (int ti = wave; ti < 60; ti += 4) {
        if (ti < 16) {
            const int isV = (ti >= 8), tile = ti & 7;
            mm_tile<4, PACKED, 0>(fin, PF,
                PACKED ? (const void*)(P.ws + (isV ? B_VW0 : B_UW0)) : (isV ? P.Vw0 : P.Uw0),
                128, tile, lane, 0.08838834764831845f,
                isV ? bcom + 128 : bcom, uv + (isV ? 480 : 0), PUV, nullptr, isf32);
        } else if (ti < 40) {
            int e = ti - 16; const int isV = (e >= 12); if (isV) e -= 12;
            const int ch = e >> 2, tile = e & 3;
            mm_tile<2, PACKED, 0>(fin + 128 + 64 * ch, PF,
                PACKED ? (const void*)(P.ws + (isV ? B_VW1 : B_UW1)) : (isV ? P.Vw1 : P.Uw1),
                64, tile, lane, 0.125f, nullptr,
                uv + (isV ? 608 : 128) + 64 * ch, PUV, nullptr, isf32);
        } else {
            int e = ti - 40; const int isV = (e >= 10); if (isV) e -= 10;
            const int ch = e >> 1, tile = e & 1;
            mm_tile<1, PACKED, 0>(fin + 320 + 32 * ch, PF,
                PACKED ? (const void*)(P.ws + (isV ? B_VW2 : B_UW2)) : (isV ? P.Vw2 : P.Uw2),
                32, tile, lane, 0.17677669529663687f, nullptr,
                uv + (isV ? 800 : 320) + 32 * ch, PUV, nullptr, isf32);
        }
    }
    __syncthreads();

    // ---------------- stage 3: inv -> scb[.,128..351] ----------------
    for (int idx = tid; idx < RPB * 224; idx += 256) {
        const int r2 = idx / 224, j = idx - r2 * 224;
        const float* V = uv + r2 * PUV + 480;
        float v;
        if (j < 128) v = fabsf(V[j]);
        else if (j < 192) {
            const int i = j - 128; float s = 0.f;
            #pragma unroll
            for (int k = 0; k < 3; ++k) { const float t = V[128 + 64 * k + i]; s += t * t; }
            v = sqrtf(s);
        } else {
            const int i = j - 192; float s = 0.f;
            #pragma unroll
            for (int k = 0; k < 5; ++k) { const float t = V[320 + 32 * k + i]; s += t * t; }
            v = sqrtf(s);
        }
        scb[r2 * PS + 128 + j] = f2bf(v);
    }
    __syncthreads();

    // ---------------- stage 4: mlp1 + silu -> hb ----------------
    for (int ti = wave; ti < 8; ti += 4)
        mm_tile<11, PACKED, 1>(scb, PS, PACKED ? (const void*)(P.ws + B_W1) : P.w1,
                               128, ti, lane, 1.f, bcom + 256, nullptr, 0, hb, isf32);
    __syncthreads();

    // ---------------- stage 5: dot (elementwise) + mlp2 ----------------
    for (int idx = tid; idx < RPB * 224; idx += 256) {
        const int r2 = idx / 224, j = idx - r2 * 224;
        const float* U = uv + r2 * PUV;
        const float* V = U + 480;
        float d;
        if (j < 128) d = U[j] * V[j];
        else if (j < 192) {
            const int i = j - 128; float s = 0.f;
            #pragma unroll
            for (int k = 0; k < 3; ++k) s += U[128 + 64 * k + i] * V[128 + 64 * k + i];
            d = s * 0.5773502691896258f;
        } else {
            const int i = j - 192; float s = 0.f;
            #pragma unroll
            for (int k = 0; k < 5; ++k) s += U[320 + 32 * k + i] * V[320 + 32 * k + i];
            d = s * 0.4472135954999579f;
        }
        dotb[r2 * PD + j] = f2bf(d);
    }
    for (int ti = wave; ti < 30; ti += 4)
        mm_tile<4, PACKED, 0>(hb, PH, PACKED ? (const void*)(P.ws + B_W2) : P.w2,
                              480, ti, lane, 1.f, bcom + 384, aout, PA, nullptr, isf32);
    __syncthreads();

    // ---------------- stage 6: inner = dot @ dot_w ----------------
    for (int ti = wave; ti < 8; ti += 4)
        mm_tile<7, PACKED, 0>(dotb, PD, PACKED ? (const void*)(P.ws + B_DW) : P.dw,
                              128, ti, lane, 1.f, nullptr, inner, PI, nullptr, isf32);
    __syncthreads();

    // ---------------- stage 7: outputs ----------------
    if (isf32) stage7_core<1>(P, uv, aout, inner, tid, row0);
    else       stage7_core<0>(P, uv, aout, inner, tid, row0);
}

extern "C" void kernel_launch(void* const* d_in, const int* in_sizes, int n_in,
                              void* d_out, int out_size, void* d_ws, size_t ws_size,
                              hipStream_t stream)
{
    Ptrs P;
    P.xs  = d_in[0];  P.xp  = d_in[1];
    P.lng = d_in[2];  P.lnb = d_in[3];
    P.o3w = d_in[4];  P.o3b = d_in[5];
    P.Uw0 = d_in[6];  P.Uw1 = d_in[7];
    P.Uw2 = d_in[8];  P.Ub0 = d_in[9];
    P.Vw0 = d_in[10]; P.Vw1 = d_in[11];
    P.Vw2 = d_in[12]; P.Vb0 = d_in[13];
    P.dw  = d_in[14]; P.w1  = d_in[15];
    P.b1  = d_in[16]; P.w2  = d_in[17];
    P.b2  = d_in[18];
    P.ws  = (const u16*)d_ws;
    P.out = d_out;

    const bool packed = (ws_size >= (size_t)PACK_TOT * sizeof(u16));
    if (packed) {
        pack_weights<<<(PACK_TOT + 255) / 256, 256, 0, stream>>>(P, (u16*)d_ws);
        xpainn_main<true><<<NBLK, 256, 0, stream>>>(P);
    } else {
        xpainn_main<false><<<NBLK, 256, 0, stream>>>(P);
    }
}

// Round 3
// 293.886 us; speedup vs baseline: 2.5012x; 2.5012x over previous
//
#include <hip/hip_runtime.h>
#include <stdint.h>

typedef unsigned short u16;
typedef __attribute__((ext_vector_type(2))) unsigned short u16x2;
typedef __attribute__((ext_vector_type(4))) unsigned short u16x4;
typedef __attribute__((ext_vector_type(8))) short s16x8;   // 8 bf16 (MFMA A/B frag)
typedef __attribute__((ext_vector_type(2))) float f32x2;
typedef __attribute__((ext_vector_type(4))) float f32x4;   // MFMA C/D frag

#define NROWS 100000
#define RPB   16
#define NBLK  (NROWS / RPB)   // 6250 exact
#define NTHR  512

// LDS pitches (elements)
#define PF   488   // fin  (bf16) channel-major [s0 128 | s1 k*64+i | s2 k*32+i]
#define PS   360   // scb  (bf16) mlp_in = [scalar_in 128 | inv 224]
#define PH   136   // hb   (bf16) silu hidden 128
#define PD   232   // dotb (bf16) dot 224
#define PUVB 968   // uv   (bf16) [U 0..479 | V 480..959]
#define PAB  484   // aout (bf16) mlp_out 480
#define PIF  132   // inner(f32)  128

// LDS arena offsets (bytes) — overlaid live ranges:
//   fin: S1-S2   aout: S5-S6   (Region1)
//   scb: S1-S4   inner: S5-S6  (Region2)
#define OFF_FIN   0        // 16*488*2 = 15616
#define OFF_AOUT  0        // 16*484*2 = 15488  (overlay w/ fin)
#define OFF_SCB   15616    // 16*360*2 = 11520
#define OFF_INNER 15616    // 16*132*4 = 8448   (overlay w/ scb)
#define OFF_HB    27136    // 16*136*2 = 4352
#define OFF_DOTB  31488    // 16*232*2 = 7424
#define OFF_UV    38912    // 16*968*2 = 30976
#define OFF_BCOM  69888    // 864*4    = 3456
#define ARENA_SZ  73344

// packed-weight bases (elements) in d_ws (always bf16 after pack)
#define B_UW0 0
#define B_UW1 16384
#define B_UW2 20480
#define B_VW0 21504
#define B_VW1 37888
#define B_VW2 41984
#define B_DW  43008
#define B_W1  71680
#define B_W2  116736
#define PACK_TOT 178176

__device__ inline float bf2f(u16 u) {
    union { uint32_t i; float f; } v; v.i = (uint32_t)u << 16; return v.f;
}
__device__ inline u16 f2bf(float f) {  // round-to-nearest-even
    union { float f; uint32_t i; } v; v.f = f;
    return (u16)((v.i + 0x7fffu + ((v.i >> 16) & 1u)) >> 16);
}
__device__ inline float wsum32(float v) {  // sum within each 32-lane half
    #pragma unroll
    for (int m = 16; m >= 1; m >>= 1) v += __shfl_xor(v, m);
    return v;
}
__device__ inline bool detect_f32(const void* xs) {
    const u16 v = ((const u16*)xs)[threadIdx.x & 63];
    const float f = bf2f(v);
    return __any(!(fabsf(f) < 1e10f)) != 0;
}
__device__ inline float ldin(const void* p, size_t i, bool f32) {
    return f32 ? ((const float*)p)[i] : bf2f(((const u16*)p)[i]);
}

struct Ptrs {
    const void *xs, *xp, *lng, *lnb, *o3w, *o3b;
    const void *Uw0, *Uw1, *Uw2, *Ub0, *Vw0, *Vw1, *Vw2, *Vb0;
    const void *dw, *w1, *b1, *w2, *b2;
    const u16 *ws;
    void *out;
};

// One 16x16 output tile, K = KS*32, bf16 MFMA.
// A: LDS row-major bf16; B: packed frags (ws, bf16) or raw row-major global.
// TYPE 0: bf16 out = acc*scale + bias   TYPE 1: bf16 out = silu(acc+bias)   TYPE 2: f32 out = acc
template<int KS, bool PACKED, int TYPE>
__device__ inline void mm_tile(const u16* A, int pitchA, const void* W, int D,
                               int tile, int lane, float scale, const float* bias,
                               void* outP, int outPitch, bool wf32)
{
    f32x4 acc = {0.f, 0.f, 0.f, 0.f};
    const int r = lane & 15, g = lane >> 4;
    const u16* arow = A + r * pitchA + g * 8;
    #pragma unroll
    for (int ks = 0; ks < KS; ++ks) {
        s16x8 a = *(const s16x8*)(arow + ks * 32);
        s16x8 b;
        if (PACKED) {
            b = *(const s16x8*)((const u16*)W + (((size_t)tile * KS + ks) * 64 + (size_t)lane) * 8);
        } else {
            union { u16 u[8]; s16x8 v; } bb;
            const int k0 = ks * 32 + g * 8, o = tile * 16 + r;
            #pragma unroll
            for (int j = 0; j < 8; ++j) {
                const size_t idx = (size_t)(k0 + j) * D + o;
                bb.u[j] = wf32 ? f2bf(((const float*)W)[idx]) : ((const u16*)W)[idx];
            }
            b = bb.v;
        }
        acc = __builtin_amdgcn_mfma_f32_16x16x32_bf16(a, b, acc, 0, 0, 0);
    }
    const int o = tile * 16 + r;
    if (TYPE == 0) {
        const float bv = bias ? bias[o] : 0.f;
        #pragma unroll
        for (int q = 0; q < 4; ++q)
            ((u16*)outP)[(size_t)(g * 4 + q) * outPitch + o] = f2bf(acc[q] * scale + bv);
    } else if (TYPE == 1) {
        const float bv = bias[o];
        #pragma unroll
        for (int q = 0; q < 4; ++q) {
            float x = acc[q] + bv;
            ((u16*)outP)[(size_t)(g * 4 + q) * outPitch + o] = f2bf(x / (1.f + expf(-x)));
        }
    } else {
        #pragma unroll
        for (int q = 0; q < 4; ++q)
            ((float*)outP)[(size_t)(g * 4 + q) * outPitch + o] = acc[q];
    }
}

__global__ void pack_weights(Ptrs P, u16* ws)
{
    const bool wf32 = detect_f32(P.xs);
    const int gid = blockIdx.x * 256 + threadIdx.x;
    if (gid >= PACK_TOT) return;
    const int  base[10] = {B_UW0, B_UW1, B_UW2, B_VW0, B_VW1, B_VW2, B_DW, B_W1, B_W2, PACK_TOT};
    const int  Kd[9]    = {128, 64, 32, 128, 64, 32, 224, 352, 128};
    const void* srcs[9] = {P.Uw0, P.Uw1, P.Uw2, P.Vw0, P.Vw1, P.Vw2, P.dw, P.w1, P.w2};
    const int  Dstride[9] = {128, 64, 32, 128, 64, 32, 128, 128, 480};
    int m = 0;
    for (int i = 1; i < 9; ++i) if (gid >= base[i]) m = i;
    const int e = gid - base[m];
    const int j = e & 7, lane = (e >> 3) & 63, tk = e >> 9;
    const int Ks = Kd[m] >> 5;
    const int ks = tk % Ks, tile = tk / Ks;
    const int k = ks * 32 + ((lane >> 4) << 3) + j;
    const int o = tile * 16 + (lane & 15);
    const size_t idx = (size_t)k * Dstride[m] + o;
    ws[gid] = wf32 ? f2bf(((const float*)srcs[m])[idx]) : ((const u16*)srcs[m])[idx];
}

// ---------------- stage 1: scalar LN + O3 layernorm (one row per half-wave) ----------------
template<int DT>
__device__ inline void stage1_core(const Ptrs& P, u16* fin, u16* scb, int tid, int row0)
{
    const int rr = tid >> 5, l32 = tid & 31;
    const size_t row = (size_t)(row0 + rr);
    const u16*   xsb = (const u16*)P.xs + row * 128;
    const float* xsf = (const float*)P.xs + row * 128;
    const u16*   xpb = (const u16*)P.xp + row * 480;
    const float* xpf = (const float*)P.xp + row * 480;
    {   // scalar layernorm -> scb[rr][0..127]
        float v[4];
        if (DT) { f32x4 u = *(const f32x4*)(xsf + l32 * 4); v[0]=u[0];v[1]=u[1];v[2]=u[2];v[3]=u[3]; }
        else    { u16x4 u = *(const u16x4*)(xsb + l32 * 4);
                  v[0]=bf2f(u[0]);v[1]=bf2f(u[1]);v[2]=bf2f(u[2]);v[3]=bf2f(u[3]); }
        float s  = v[0] + v[1] + v[2] + v[3];
        float s2 = v[0]*v[0] + v[1]*v[1] + v[2]*v[2] + v[3]*v[3];
        s = wsum32(s); s2 = wsum32(s2);
        const float mu = s * (1.f / 128.f);
        const float rs = 1.f / sqrtf(s2 * (1.f / 128.f) - mu * mu + 1e-5f);
        const int c = l32 * 4;
        #pragma unroll
        for (int j2 = 0; j2 < 4; ++j2)
            scb[rr * PS + c + j2] =
                f2bf((v[j2] - mu) * rs * ldin(P.lng, c + j2, DT) + ldin(P.lnb, c + j2, DT));
    }
    {   // s0 O3-LN -> fin[rr][0..127]
        float v[4];
        if (DT) { f32x4 u = *(const f32x4*)(xpf + l32 * 4); v[0]=u[0];v[1]=u[1];v[2]=u[2];v[3]=u[3]; }
        else    { u16x4 u = *(const u16x4*)(xpb + l32 * 4);
                  v[0]=bf2f(u[0]);v[1]=bf2f(u[1]);v[2]=bf2f(u[2]);v[3]=bf2f(u[3]); }
        float s  = v[0] + v[1] + v[2] + v[3];
        float s2 = v[0]*v[0] + v[1]*v[1] + v[2]*v[2] + v[3]*v[3];
        s = wsum32(s); s2 = wsum32(s2);
        const float mu = s * (1.f / 128.f);
        const float rs = 1.f / sqrtf(s2 * (1.f / 128.f) - mu * mu + 1e-5f);
        const int c = l32 * 4;
        #pragma unroll
        for (int j2 = 0; j2 < 4; ++j2)
            fin[rr * PF + c + j2] =
                f2bf((v[j2] - mu) * rs * ldin(P.o3w, c + j2, DT) + ldin(P.o3b, c + j2, DT));
    }
    {   // s1 (64 irreps x 3) -> fin[rr][128 + k*64 + i]
        const int cb = l32 * 6;
        float w[6];
        if (DT) {
            f32x2 a0 = *(const f32x2*)(xpf + 128 + cb);
            f32x2 a1 = *(const f32x2*)(xpf + 128 + cb + 2);
            f32x2 a2 = *(const f32x2*)(xpf + 128 + cb + 4);
            w[0]=a0[0]; w[1]=a0[1]; w[2]=a1[0]; w[3]=a1[1]; w[4]=a2[0]; w[5]=a2[1];
        } else {
            u16x2 a0 = *(const u16x2*)(xpb + 128 + cb);
            u16x2 a1 = *(const u16x2*)(xpb + 128 + cb + 2);
            u16x2 a2 = *(const u16x2*)(xpb + 128 + cb + 4);
            w[0]=bf2f(a0[0]); w[1]=bf2f(a0[1]); w[2]=bf2f(a1[0]);
            w[3]=bf2f(a1[1]); w[4]=bf2f(a2[0]); w[5]=bf2f(a2[1]);
        }
        float ss = 0.f;
        #pragma unroll
        for (int j2 = 0; j2 < 6; ++j2) ss += w[j2] * w[j2];
        ss = wsum32(ss);
        const float rs = 1.f / sqrtf(ss * (1.f / 192.f) + 1e-5f);
        #pragma unroll
        for (int j2 = 0; j2 < 6; ++j2) {
            const int c = cb + j2, i = c / 3, k = c - 3 * i;
            fin[rr * PF + 128 + k * 64 + i] = f2bf(w[j2] * rs * ldin(P.o3w, 128 + i, DT));
        }
    }
    {   // s2 (32 irreps x 5) -> fin[rr][320 + k*32 + i]
        const int cb = l32 * 5;
        float w[5];
        #pragma unroll
        for (int j2 = 0; j2 < 5; ++j2)
            w[j2] = DT ? xpf[320 + cb + j2] : bf2f(xpb[320 + cb + j2]);
        float ss = 0.f;
        #pragma unroll
        for (int j2 = 0; j2 < 5; ++j2) ss += w[j2] * w[j2];
        ss = wsum32(ss);
        const float rs = 1.f / sqrtf(ss * (1.f / 160.f) + 1e-5f);
        #pragma unroll
        for (int j2 = 0; j2 < 5; ++j2) {
            const int c = cb + j2, i = c / 5, k = c - 5 * i;
            fin[rr * PF + 320 + k * 32 + i] = f2bf(w[j2] * rs * ldin(P.o3w, 192 + i, DT));
        }
    }
}

// ---------------- stage 6: outputs ----------------
template<int DT>
__device__ inline void stage6_core(const Ptrs& P, const u16* uvB, const u16* aoutB,
                                   const float* innerF, int tid, int row0)
{
    for (int idx = tid; idx < RPB * 128; idx += NTHR) {
        const int r2 = idx >> 7, c = idx & 127;
        const size_t row = (size_t)(row0 + r2);
        const float xs = ldin(P.xs, row * 128 + c, DT);
        const float val = xs + bf2f(aoutB[r2 * PAB + 224 + c]) * innerF[r2 * PIF + c]
                             + bf2f(aoutB[r2 * PAB + 352 + c]);
        if (DT) ((float*)P.out)[row * 128 + c] = val;
        else    ((u16*)P.out)[row * 128 + c] = f2bf(val);
    }
    for (int idx = tid; idx < RPB * 480; idx += NTHR) {
        const int r2 = idx / 480, c = idx - r2 * 480;
        const size_t row = (size_t)(row0 + r2);
        float u, av;
        if (c < 128)      { u = bf2f(uvB[r2 * PUVB + c]);                av = bf2f(aoutB[r2 * PAB + c]); }
        else if (c < 320) { const int e = c - 128, i = e / 3, k = e - 3 * i;
                            u = bf2f(uvB[r2 * PUVB + 128 + 64 * k + i]); av = bf2f(aoutB[r2 * PAB + 128 + i]); }
        else              { const int e = c - 320, i = e / 5, k = e - 5 * i;
                            u = bf2f(uvB[r2 * PUVB + 320 + 32 * k + i]); av = bf2f(aoutB[r2 * PAB + 192 + i]); }
        const float val = ldin(P.xp, row * 480 + c, DT) + u * av;
        const size_t oi = (size_t)NROWS * 128 + row * 480 + c;
        if (DT) ((float*)P.out)[oi] = val;
        else    ((u16*)P.out)[oi] = f2bf(val);
    }
}

template<bool PACKED>
__global__ __launch_bounds__(NTHR, 4) void xpainn_main(Ptrs P)
{
    __shared__ __align__(16) unsigned char arena[ARENA_SZ];
    u16*   fin    = (u16*)(arena + OFF_FIN);
    u16*   aoutB  = (u16*)(arena + OFF_AOUT);
    u16*   scb    = (u16*)(arena + OFF_SCB);
    float* innerF = (float*)(arena + OFF_INNER);
    u16*   hb     = (u16*)(arena + OFF_HB);
    u16*   dotb   = (u16*)(arena + OFF_DOTB);
    u16*   uvB    = (u16*)(arena + OFF_UV);
    float* bcom   = (float*)(arena + OFF_BCOM);   // [Ub0 | Vb0 | b1 | b2(480)]

    const int tid = threadIdx.x;
    const int lane = tid & 63, wave = tid >> 6;
    const int row0 = blockIdx.x * RPB;
    const bool isf32 = detect_f32(P.xs);

    // bias vectors -> LDS f32
    for (int i = tid; i < 864; i += NTHR) {
        const void* src; int off;
        if (i < 128)      { src = P.Ub0; off = i; }
        else if (i < 256) { src = P.Vb0; off = i - 128; }
        else if (i < 384) { src = P.b1;  off = i - 256; }
        else              { src = P.b2;  off = i - 384; }
        bcom[i] = ldin(src, off, isf32);
    }
    if (isf32) stage1_core<1>(P, fin, scb, tid, row0);
    else       stage1_core<0>(P, fin, scb, tid, row0);
    __syncthreads();

    // ---------------- S2: U,V O3-linears -> uvB ----------------
    for (int ti = wave; ti < 60; ti += 8) {
        if (ti < 16) {
            const int isV = (ti >= 8), tile = ti & 7;
            mm_tile<4, PACKED, 0>(fin, PF,
                PACKED ? (const void*)(P.ws + (isV ? B_VW0 : B_UW0)) : (isV ? P.Vw0 : P.Uw0),
                128, tile, lane, 0.08838834764831845f,
                isV ? bcom + 128 : bcom, uvB + (isV ? 480 : 0), PUVB, isf32);
        } else if (ti < 40) {
            int e = ti - 16; const int isV = (e >= 12); if (isV) e -= 12;
            const int ch = e >> 2, tile = e & 3;
            mm_tile<2, PACKED, 0>(fin + 128 + 64 * ch, PF,
                PACKED ? (const void*)(P.ws + (isV ? B_VW1 : B_UW1)) : (isV ? P.Vw1 : P.Uw1),
                64, tile, lane, 0.125f, nullptr,
                uvB + (isV ? 608 : 128) + 64 * ch, PUVB, isf32);
        } else {
            int e = ti - 40; const int isV = (e >= 10); if (isV) e -= 10;
            const int ch = e >> 1, tile = e & 1;
            mm_tile<1, PACKED, 0>(fin + 320 + 32 * ch, PF,
                PACKED ? (const void*)(P.ws + (isV ? B_VW2 : B_UW2)) : (isV ? P.Vw2 : P.Uw2),
                32, tile, lane, 0.17677669529663687f, nullptr,
                uvB + (isV ? 800 : 320) + 32 * ch, PUVB, isf32);
        }
    }
    __syncthreads();

    // ---------------- S3: inv -> scb[.,128..351]  AND  dot -> dotb (shared U/V loads) ----------------
    for (int idx = tid; idx < RPB * 224; idx += NTHR) {
        const int r2 = idx / 224, j = idx - r2 * 224;
        const u16* U = uvB + r2 * PUVB;
        const u16* V = U + 480;
        float inv, dot;
        if (j < 128) {
            const float v = bf2f(V[j]);
            inv = fabsf(v);
            dot = bf2f(U[j]) * v;
        } else if (j < 192) {
            const int i = j - 128; float sv = 0.f, suv = 0.f;
            #pragma unroll
            for (int k = 0; k < 3; ++k) {
                const float v = bf2f(V[128 + 64 * k + i]), u = bf2f(U[128 + 64 * k + i]);
                sv += v * v; suv += u * v;
            }
            inv = sqrtf(sv);
            dot = suv * 0.5773502691896258f;   // 1/sqrt(3)
        } else {
            const int i = j - 192; float sv = 0.f, suv = 0.f;
            #pragma unroll
            for (int k = 0; k < 5; ++k) {
                const float v = bf2f(V[320 + 32 * k + i]), u = bf2f(U[320 + 32 * k + i]);
                sv += v * v; suv += u * v;
            }
            inv = sqrtf(sv);
            dot = suv * 0.4472135954999579f;   // 1/sqrt(5)
        }
        scb[r2 * PS + 128 + j] = f2bf(inv);
        dotb[r2 * PD + j] = f2bf(dot);
    }
    __syncthreads();

    // ---------------- S4: mlp1 + silu -> hb ----------------
    for (int ti = wave; ti < 8; ti += 8)
        mm_tile<11, PACKED, 1>(scb, PS, PACKED ? (const void*)(P.ws + B_W1) : P.w1,
                               128, ti, lane, 1.f, bcom + 256, hb, PH, isf32);
    __syncthreads();

    // ---------------- S5: mlp2 -> aoutB  AND  inner = dot @ dot_w -> innerF ----------------
    for (int ti = wave; ti < 38; ti += 8) {
        if (ti < 30)
            mm_tile<4, PACKED, 0>(hb, PH, PACKED ? (const void*)(P.ws + B_W2) : P.w2,
                                  480, ti, lane, 1.f, bcom + 384, aoutB, PAB, isf32);
        else
            mm_tile<7, PACKED, 2>(dotb, PD, PACKED ? (const void*)(P.ws + B_DW) : P.dw,
                                  128, ti - 30, lane, 1.f, nullptr, innerF, PIF, isf32);
    }
    __syncthreads();

    // ---------------- S6: outputs ----------------
    if (isf32) stage6_core<1>(P, uvB, aoutB, innerF, tid, row0);
    else       stage6_core<0>(P, uvB, aoutB, innerF, tid, row0);
}

extern "C" void kernel_launch(void* const* d_in, const int* in_sizes, int n_in,
                              void* d_out, int out_size, void* d_ws, size_t ws_size,
                              hipStream_t stream)
{
    Ptrs P;
    P.xs  = d_in[0];  P.xp  = d_in[1];
    P.lng = d_in[2];  P.lnb = d_in[3];
    P.o3w = d_in[4];  P.o3b = d_in[5];
    P.Uw0 = d_in[6];  P.Uw1 = d_in[7];
    P.Uw2 = d_in[8];  P.Ub0 = d_in[9];
    P.Vw0 = d_in[10]; P.Vw1 = d_in[11];
    P.Vw2 = d_in[12]; P.Vb0 = d_in[13];
    P.dw  = d_in[14]; P.w1  = d_in[15];
    P.b1  = d_in[16]; P.w2  = d_in[17];
    P.b2  = d_in[18];
    P.ws  = (const u16*)d_ws;
    P.out = d_out;

    const bool packed = (ws_size >= (size_t)PACK_TOT * sizeof(u16));
    if (packed) {
        pack_weights<<<(PACK_TOT + 255) / 256, 256, 0, stream>>>(P, (u16*)d_ws);
        xpainn_main<true><<<NBLK, NTHR, 0, stream>>>(P);
    } else {
        xpainn_main<false><<<NBLK, NTHR, 0, stream>>>(P);
    }
}

// Round 4
// 284.792 us; speedup vs baseline: 2.5810x; 1.0319x over previous
//
#include <hip/hip_runtime.h>
#include <stdint.h>

typedef unsigned short u16;
typedef __attribute__((ext_vector_type(2))) unsigned short u16x2;
typedef __attribute__((ext_vector_type(4))) unsigned short u16x4;
typedef __attribute__((ext_vector_type(8))) short s16x8;   // 8 bf16 (MFMA A/B frag)
typedef __attribute__((ext_vector_type(2))) float f32x2;
typedef __attribute__((ext_vector_type(4))) float f32x4;   // MFMA C/D frag

#define NROWS 100000
#define RPB   16
#define NBLK  (NROWS / RPB)   // 6250 exact
#define NTHR  512

// LDS pitches (elements)
#define PF   488   // fin  (bf16) channel-major [s0 128 | s1 k*64+i | s2 k*32+i]
#define PS   360   // scb  (bf16) mlp_in = [scalar_in 128 | inv 224]
#define PH   136   // hb   (bf16) silu hidden 128
#define PD   232   // dotb (bf16) dot 224
#define PAB  484   // aout (bf16) mlp_out 480
#define PIF  132   // inner(f32)  128

// LDS arena (bytes), overlaid live ranges:
//   fin  S1->S2   aout  S5->S6   (region A)
//   scb  S1->S4   inner S5->S6   (region B)
#define OFF_FIN   0        // 16*488*2 = 15616  (aout: 16*484*2 = 15488)
#define OFF_AOUT  0
#define OFF_SCB   15616    // 16*360*2 = 11520  (inner: 16*132*4 = 8448)
#define OFF_INNER 15616
#define OFF_DOTB  27136    // 16*232*2 = 7424   (S2 -> S5)
#define OFF_HB    34560    // 16*136*2 = 4352   (S4 -> S5)
#define OFF_BCOM  38912    // 864*2    = 1728   (bf16 biases)
#define ARENA_SZ  40640    // -> 4 blocks/CU (160 KiB LDS)

// packed-weight bases (elements) in d_ws (always bf16 after pack)
#define B_UW0 0
#define B_UW1 16384
#define B_UW2 20480
#define B_VW0 21504
#define B_VW1 37888
#define B_VW2 41984
#define B_DW  43008
#define B_W1  71680
#define B_W2  116736
#define PACK_TOT 178176

__device__ inline float bf2f(u16 u) {
    union { uint32_t i; float f; } v; v.i = (uint32_t)u << 16; return v.f;
}
__device__ inline u16 f2bf(float f) {  // round-to-nearest-even
    union { float f; uint32_t i; } v; v.f = f;
    return (u16)((v.i + 0x7fffu + ((v.i >> 16) & 1u)) >> 16);
}
__device__ inline float wsum32(float v) {
    #pragma unroll
    for (int m = 16; m >= 1; m >>= 1) v += __shfl_xor(v, m);
    return v;
}
__device__ inline bool detect_f32(const void* xs) {
    const u16 v = ((const u16*)xs)[threadIdx.x & 63];
    const float f = bf2f(v);
    return __any(!(fabsf(f) < 1e10f)) != 0;
}
__device__ inline float ldin(const void* p, size_t i, bool f32) {
    return f32 ? ((const float*)p)[i] : bf2f(((const u16*)p)[i]);
}
__device__ inline void stout(void* p, size_t i, float v, bool f32) {
    if (f32) ((float*)p)[i] = v; else ((u16*)p)[i] = f2bf(v);
}

struct Ptrs {
    const void *xs, *xp, *lng, *lnb, *o3w, *o3b;
    const void *Uw0, *Uw1, *Uw2, *Ub0, *Vw0, *Vw1, *Vw2, *Vb0;
    const void *dw, *w1, *b1, *w2, *b2;
    const u16 *ws;
    void *out;
};

// Raw accumulate of one 16x16 tile, K = KS*32. Returns unscaled acc.
template<int KS, bool PACKED>
__device__ inline f32x4 mm_acc(const u16* A, int pitchA, const void* W, int D,
                               int tile, int lane, bool wf32)
{
    f32x4 acc = {0.f, 0.f, 0.f, 0.f};
    const int r = lane & 15, g = lane >> 4;
    const u16* arow = A + r * pitchA + g * 8;
    #pragma unroll
    for (int ks = 0; ks < KS; ++ks) {
        s16x8 a = *(const s16x8*)(arow + ks * 32);
        s16x8 b;
        if (PACKED) {
            b = *(const s16x8*)((const u16*)W + (((size_t)tile * KS + ks) * 64 + (size_t)lane) * 8);
        } else {
            union { u16 u[8]; s16x8 v; } bb;
            const int k0 = ks * 32 + g * 8, o = tile * 16 + r;
            #pragma unroll
            for (int j = 0; j < 8; ++j) {
                const size_t idx = (size_t)(k0 + j) * D + o;
                bb.u[j] = wf32 ? f2bf(((const float*)W)[idx]) : ((const u16*)W)[idx];
            }
            b = bb.v;
        }
        acc = __builtin_amdgcn_mfma_f32_16x16x32_bf16(a, b, acc, 0, 0, 0);
    }
    return acc;
}

// Tile + epilogue. TYPE 0: bf16 out = acc*scale + bias  TYPE 1: bf16 out = silu(acc+bias)
// TYPE 2: f32 out = acc
template<int KS, bool PACKED, int TYPE>
__device__ inline void mm_tile(const u16* A, int pitchA, const void* W, int D,
                               int tile, int lane, float scale, const u16* bias,
                               void* outP, int outPitch, bool wf32)
{
    f32x4 acc = mm_acc<KS, PACKED>(A, pitchA, W, D, tile, lane, wf32);
    const int r = lane & 15, g = lane >> 4;
    const int o = tile * 16 + r;
    if (TYPE == 0) {
        const float bv = bias ? bf2f(bias[o]) : 0.f;
        #pragma unroll
        for (int q = 0; q < 4; ++q)
            ((u16*)outP)[(size_t)(g * 4 + q) * outPitch + o] = f2bf(acc[q] * scale + bv);
    } else if (TYPE == 1) {
        const float bv = bf2f(bias[o]);
        #pragma unroll
        for (int q = 0; q < 4; ++q) {
            float x = acc[q] + bv;
            ((u16*)outP)[(size_t)(g * 4 + q) * outPitch + o] = f2bf(x / (1.f + expf(-x)));
        }
    } else {
        #pragma unroll
        for (int q = 0; q < 4; ++q)
            ((float*)outP)[(size_t)(g * 4 + q) * outPitch + o] = acc[q];
    }
}

__global__ void pack_weights(Ptrs P, u16* ws)
{
    const bool wf32 = detect_f32(P.xs);
    const int gid = blockIdx.x * 256 + threadIdx.x;
    if (gid >= PACK_TOT) return;
    const int  base[10] = {B_UW0, B_UW1, B_UW2, B_VW0, B_VW1, B_VW2, B_DW, B_W1, B_W2, PACK_TOT};
    const int  Kd[9]    = {128, 64, 32, 128, 64, 32, 224, 352, 128};
    const void* srcs[9] = {P.Uw0, P.Uw1, P.Uw2, P.Vw0, P.Vw1, P.Vw2, P.dw, P.w1, P.w2};
    const int  Dstride[9] = {128, 64, 32, 128, 64, 32, 128, 128, 480};
    int m = 0;
    for (int i = 1; i < 9; ++i) if (gid >= base[i]) m = i;
    const int e = gid - base[m];
    const int j = e & 7, lane = (e >> 3) & 63, tk = e >> 9;
    const int Ks = Kd[m] >> 5;
    const int ks = tk % Ks, tile = tk / Ks;
    const int k = ks * 32 + ((lane >> 4) << 3) + j;
    const int o = tile * 16 + (lane & 15);
    const size_t idx = (size_t)k * Dstride[m] + o;
    ws[gid] = wf32 ? f2bf(((const float*)srcs[m])[idx]) : ((const u16*)srcs[m])[idx];
}

// ---------------- stage 1: scalar LN + O3 layernorm (one row per half-wave) ----------------
template<int DT>
__device__ inline void stage1_core(const Ptrs& P, u16* fin, u16* scb, int tid, int row0)
{
    const int rr = tid >> 5, l32 = tid & 31;
    const size_t row = (size_t)(row0 + rr);
    const u16*   xsb = (const u16*)P.xs + row * 128;
    const float* xsf = (const float*)P.xs + row * 128;
    const u16*   xpb = (const u16*)P.xp + row * 480;
    const float* xpf = (const float*)P.xp + row * 480;
    {   // scalar layernorm -> scb[rr][0..127]
        float v[4];
        if (DT) { f32x4 u = *(const f32x4*)(xsf + l32 * 4); v[0]=u[0];v[1]=u[1];v[2]=u[2];v[3]=u[3]; }
        else    { u16x4 u = *(const u16x4*)(xsb + l32 * 4);
                  v[0]=bf2f(u[0]);v[1]=bf2f(u[1]);v[2]=bf2f(u[2]);v[3]=bf2f(u[3]); }
        float s  = v[0] + v[1] + v[2] + v[3];
        float s2 = v[0]*v[0] + v[1]*v[1] + v[2]*v[2] + v[3]*v[3];
        s = wsum32(s); s2 = wsum32(s2);
        const float mu = s * (1.f / 128.f);
        const float rs = 1.f / sqrtf(s2 * (1.f / 128.f) - mu * mu + 1e-5f);
        const int c = l32 * 4;
        #pragma unroll
        for (int j2 = 0; j2 < 4; ++j2)
            scb[rr * PS + c + j2] =
                f2bf((v[j2] - mu) * rs * ldin(P.lng, c + j2, DT) + ldin(P.lnb, c + j2, DT));
    }
    {   // s0 O3-LN -> fin[rr][0..127]
        float v[4];
        if (DT) { f32x4 u = *(const f32x4*)(xpf + l32 * 4); v[0]=u[0];v[1]=u[1];v[2]=u[2];v[3]=u[3]; }
        else    { u16x4 u = *(const u16x4*)(xpb + l32 * 4);
                  v[0]=bf2f(u[0]);v[1]=bf2f(u[1]);v[2]=bf2f(u[2]);v[3]=bf2f(u[3]); }
        float s  = v[0] + v[1] + v[2] + v[3];
        float s2 = v[0]*v[0] + v[1]*v[1] + v[2]*v[2] + v[3]*v[3];
        s = wsum32(s); s2 = wsum32(s2);
        const float mu = s * (1.f / 128.f);
        const float rs = 1.f / sqrtf(s2 * (1.f / 128.f) - mu * mu + 1e-5f);
        const int c = l32 * 4;
        #pragma unroll
        for (int j2 = 0; j2 < 4; ++j2)
            fin[rr * PF + c + j2] =
                f2bf((v[j2] - mu) * rs * ldin(P.o3w, c + j2, DT) + ldin(P.o3b, c + j2, DT));
    }
    {   // s1 (64 irreps x 3) -> fin[rr][128 + k*64 + i]
        const int cb = l32 * 6;
        float w[6];
        if (DT) {
            f32x2 a0 = *(const f32x2*)(xpf + 128 + cb);
            f32x2 a1 = *(const f32x2*)(xpf + 128 + cb + 2);
            f32x2 a2 = *(const f32x2*)(xpf + 128 + cb + 4);
            w[0]=a0[0]; w[1]=a0[1]; w[2]=a1[0]; w[3]=a1[1]; w[4]=a2[0]; w[5]=a2[1];
        } else {
            u16x2 a0 = *(const u16x2*)(xpb + 128 + cb);
            u16x2 a1 = *(const u16x2*)(xpb + 128 + cb + 2);
            u16x2 a2 = *(const u16x2*)(xpb + 128 + cb + 4);
            w[0]=bf2f(a0[0]); w[1]=bf2f(a0[1]); w[2]=bf2f(a1[0]);
            w[3]=bf2f(a1[1]); w[4]=bf2f(a2[0]); w[5]=bf2f(a2[1]);
        }
        float ss = 0.f;
        #pragma unroll
        for (int j2 = 0; j2 < 6; ++j2) ss += w[j2] * w[j2];
        ss = wsum32(ss);
        const float rs = 1.f / sqrtf(ss * (1.f / 192.f) + 1e-5f);
        #pragma unroll
        for (int j2 = 0; j2 < 6; ++j2) {
            const int c = cb + j2, i = c / 3, k = c - 3 * i;
            fin[rr * PF + 128 + k * 64 + i] = f2bf(w[j2] * rs * ldin(P.o3w, 128 + i, DT));
        }
    }
    {   // s2 (32 irreps x 5) -> fin[rr][320 + k*32 + i]
        const int cb = l32 * 5;
        float w[5];
        #pragma unroll
        for (int j2 = 0; j2 < 5; ++j2)
            w[j2] = DT ? xpf[320 + cb + j2] : bf2f(xpb[320 + cb + j2]);
        float ss = 0.f;
        #pragma unroll
        for (int j2 = 0; j2 < 5; ++j2) ss += w[j2] * w[j2];
        ss = wsum32(ss);
        const float rs = 1.f / sqrtf(ss * (1.f / 160.f) + 1e-5f);
        #pragma unroll
        for (int j2 = 0; j2 < 5; ++j2) {
            const int c = cb + j2, i = c / 5, k = c - 5 * i;
            fin[rr * PF + 320 + k * 32 + i] = f2bf(w[j2] * rs * ldin(P.o3w, 192 + i, DT));
        }
    }
}

template<bool PACKED>
__global__ __launch_bounds__(NTHR, 8) void xpainn_main(Ptrs P)
{
    __shared__ __align__(16) unsigned char arena[ARENA_SZ];
    u16*   fin    = (u16*)(arena + OFF_FIN);
    u16*   aoutB  = (u16*)(arena + OFF_AOUT);
    u16*   scb    = (u16*)(arena + OFF_SCB);
    float* innerF = (float*)(arena + OFF_INNER);
    u16*   dotb   = (u16*)(arena + OFF_DOTB);
    u16*   hb     = (u16*)(arena + OFF_HB);
    u16*   bcom   = (u16*)(arena + OFF_BCOM);   // bf16 [Ub0 | Vb0 | b1 | b2(480)]

    const int tid = threadIdx.x;
    const int lane = tid & 63, wave = tid >> 6;
    const int r = lane & 15, g = lane >> 4;
    const int row0 = blockIdx.x * RPB;
    const bool isf32 = detect_f32(P.xs);

    // biases -> LDS bf16
    for (int i = tid; i < 864; i += NTHR) {
        const void* src; int off;
        if (i < 128)      { src = P.Ub0; off = i; }
        else if (i < 256) { src = P.Vb0; off = i - 128; }
        else if (i < 384) { src = P.b1;  off = i - 256; }
        else              { src = P.b2;  off = i - 384; }
        bcom[i] = f2bf(ldin(src, off, isf32));
    }
    if (isf32) stage1_core<1>(P, fin, scb, tid, row0);
    else       stage1_core<0>(P, fin, scb, tid, row0);
    __syncthreads();

    // ---------------- S2: U,V O3-linears with in-register inv/dot (S3 fused) ----------------
    // Task 1 (all waves): l0 tile = wave. Task 2: waves 0-3 l1 tile w; waves 4-5 l2 tile w-4.
    // U values stay in registers until S6; V never leaves registers.
    float u0r[4];          // l0 U, this wave's tile
    float uxr[5][4];       // l1 (3 used) or l2 (5 used) U channels
    {
        const int o = wave * 16 + r;
        f32x4 au = mm_acc<4, PACKED>(fin, PF,
            PACKED ? (const void*)(P.ws + B_UW0) : P.Uw0, 128, wave, lane, isf32);
        f32x4 av = mm_acc<4, PACKED>(fin, PF,
            PACKED ? (const void*)(P.ws + B_VW0) : P.Vw0, 128, wave, lane, isf32);
        const float bu = bf2f(bcom[o]), bv = bf2f(bcom[128 + o]);
        #pragma unroll
        for (int q = 0; q < 4; ++q) {
            const float U = au[q] * 0.08838834764831845f + bu;
            const float V = av[q] * 0.08838834764831845f + bv;
            u0r[q] = U;
            const int row = g * 4 + q;
            scb[row * PS + 128 + o]  = f2bf(fabsf(V));
            dotb[row * PD + o]       = f2bf(U * V);
        }
    }
    if (wave < 4) {                 // l1: tile tt = wave, 3 channels, K=64
        const int tt = wave, o = tt * 16 + r;
        f32x4 au[3], av[3];
        #pragma unroll
        for (int ch = 0; ch < 3; ++ch) {
            au[ch] = mm_acc<2, PACKED>(fin + 128 + 64 * ch, PF,
                PACKED ? (const void*)(P.ws + B_UW1) : P.Uw1, 64, tt, lane, isf32);
            av[ch] = mm_acc<2, PACKED>(fin + 128 + 64 * ch, PF,
                PACKED ? (const void*)(P.ws + B_VW1) : P.Vw1, 64, tt, lane, isf32);
        }
        #pragma unroll
        for (int q = 0; q < 4; ++q) {
            float sv = 0.f, suv = 0.f;
            #pragma unroll
            for (int ch = 0; ch < 3; ++ch) {
                const float U = au[ch][q] * 0.125f, V = av[ch][q] * 0.125f;
                uxr[ch][q] = U; sv += V * V; suv += U * V;
            }
            const int row = g * 4 + q;
            scb[row * PS + 256 + o]  = f2bf(sqrtf(sv));
            dotb[row * PD + 128 + o] = f2bf(suv * 0.5773502691896258f);
        }
    } else if (wave < 6) {          // l2: tile tt = wave-4, 5 channels, K=32
        const int tt = wave - 4, o = tt * 16 + r;
        f32x4 au[5], av[5];
        #pragma unroll
        for (int ch = 0; ch < 5; ++ch) {
            au[ch] = mm_acc<1, PACKED>(fin + 320 + 32 * ch, PF,
                PACKED ? (const void*)(P.ws + B_UW2) : P.Uw2, 32, tt, lane, isf32);
            av[ch] = mm_acc<1, PACKED>(fin + 320 + 32 * ch, PF,
                PACKED ? (const void*)(P.ws + B_VW2) : P.Vw2, 32, tt, lane, isf32);
        }
        #pragma unroll
        for (int q = 0; q < 4; ++q) {
            float sv = 0.f, suv = 0.f;
            #pragma unroll
            for (int ch = 0; ch < 5; ++ch) {
                const float U = au[ch][q] * 0.17677669529663687f, V = av[ch][q] * 0.17677669529663687f;
                uxr[ch][q] = U; sv += V * V; suv += U * V;
            }
            const int row = g * 4 + q;
            scb[row * PS + 320 + o]  = f2bf(sqrtf(sv));
            dotb[row * PD + 192 + o] = f2bf(suv * 0.4472135954999579f);
        }
    }
    __syncthreads();

    // ---------------- S4: mlp1 + silu -> hb ----------------
    mm_tile<11, PACKED, 1>(scb, PS, PACKED ? (const void*)(P.ws + B_W1) : P.w1,
                           128, wave, lane, 1.f, bcom + 256, hb, PH, isf32);
    __syncthreads();

    // ---------------- S5: mlp2 -> aoutB  AND  inner = dot @ dot_w -> innerF ----------------
    for (int ti = wave; ti < 38; ti += 8) {
        if (ti < 30)
            mm_tile<4, PACKED, 0>(hb, PH, PACKED ? (const void*)(P.ws + B_W2) : P.w2,
                                  480, ti, lane, 1.f, bcom + 384, aoutB, PAB, isf32);
        else
            mm_tile<7, PACKED, 2>(dotb, PD, PACKED ? (const void*)(P.ws + B_DW) : P.dw,
                                  128, ti - 30, lane, 1.f, nullptr, innerF, PIF, isf32);
    }
    __syncthreads();

    // ---------------- S6: outputs ----------------
    // scalar residual: out = xs + a_sv*inner + a_ss
    for (int idx = tid; idx < RPB * 128; idx += NTHR) {
        const int r2 = idx >> 7, c = idx & 127;
        const size_t row = (size_t)(row0 + r2);
        const float val = ldin(P.xs, row * 128 + c, isf32)
                        + bf2f(aoutB[r2 * PAB + 224 + c]) * innerF[r2 * PIF + c]
                        + bf2f(aoutB[r2 * PAB + 352 + c]);
        stout(P.out, row * 128 + c, val, isf32);
    }
    // spherical residual from in-register U: out = xp + U * a_vv
    {
        const size_t ob = (size_t)NROWS * 128;
        const int o = wave * 16 + r;     // l0 col
        #pragma unroll
        for (int q = 0; q < 4; ++q) {
            const int row = g * 4 + q;
            const size_t gr = (size_t)(row0 + row) * 480;
            const float av = bf2f(aoutB[row * PAB + o]);
            stout(P.out, ob + gr + o, ldin(P.xp, gr + o, isf32) + u0r[q] * av, isf32);
        }
        if (wave < 4) {
            const int i = wave * 16 + r;
            #pragma unroll
            for (int q = 0; q < 4; ++q) {
                const int row = g * 4 + q;
                const size_t gr = (size_t)(row0 + row) * 480;
                const float av = bf2f(aoutB[row * PAB + 128 + i]);
                #pragma unroll
                for (int ch = 0; ch < 3; ++ch) {
                    const size_t c = 128 + 3 * i + ch;
                    stout(P.out, ob + gr + c, ldin(P.xp, gr + c, isf32) + uxr[ch][q] * av, isf32);
                }
            }
        } else if (wave < 6) {
            const int i = (wave - 4) * 16 + r;
            #pragma unroll
            for (int q = 0; q < 4; ++q) {
                const int row = g * 4 + q;
                const size_t gr = (size_t)(row0 + row) * 480;
                const float av = bf2f(aoutB[row * PAB + 192 + i]);
                #pragma unroll
                for (int ch = 0; ch < 5; ++ch) {
                    const size_t c = 320 + 5 * i + ch;
                    stout(P.out, ob + gr + c, ldin(P.xp, gr + c, isf32) + uxr[ch][q] * av, isf32);
                }
            }
        }
    }
}

extern "C" void kernel_launch(void* const* d_in, const int* in_sizes, int n_in,
                              void* d_out, int out_size, void* d_ws, size_t ws_size,
                              hipStream_t stream)
{
    Ptrs P;
    P.xs  = d_in[0];  P.xp  = d_in[1];
    P.lng = d_in[2];  P.lnb = d_in[3];
    P.o3w = d_in[4];  P.o3b = d_in[5];
    P.Uw0 = d_in[6];  P.Uw1 = d_in[7];
    P.Uw2 = d_in[8];  P.Ub0 = d_in[9];
    P.Vw0 = d_in[10]; P.Vw1 = d_in[11];
    P.Vw2 = d_in[12]; P.Vb0 = d_in[13];
    P.dw  = d_in[14]; P.w1  = d_in[15];
    P.b1  = d_in[16]; P.w2  = d_in[17];
    P.b2  = d_in[18];
    P.ws  = (const u16*)d_ws;
    P.out = d_out;

    const bool packed = (ws_size >= (size_t)PACK_TOT * sizeof(u16));
    if (packed) {
        pack_weights<<<(PACK_TOT + 255) / 256, 256, 0, stream>>>(P, (u16*)d_ws);
        xpainn_main<true><<<NBLK, NTHR, 0, stream>>>(P);
    } else {
        xpainn_main<false><<<NBLK, NTHR, 0, stream>>>(P);
    }
}

// Round 5
// 244.303 us; speedup vs baseline: 3.0088x; 1.1657x over previous
//
#include <hip/hip_runtime.h>
#include <stdint.h>

typedef unsigned short u16;
typedef __attribute__((ext_vector_type(2))) unsigned short u16x2;
typedef __attribute__((ext_vector_type(4))) unsigned short u16x4;
typedef __attribute__((ext_vector_type(8))) short s16x8;   // 8 bf16 (MFMA A/B frag)
typedef __attribute__((ext_vector_type(2))) float f32x2;
typedef __attribute__((ext_vector_type(4))) float f32x4;   // MFMA C/D frag

#define NROWS 100000
#define RPB   16
#define NBLK  (NROWS / RPB)   // 6250 exact
#define NTHR  512

// LDS pitches (elements)
#define PF   488   // fin  (bf16) channel-major [s0 128 | s1 k*64+i | s2 k*32+i]
#define PS   360   // scb  (bf16) mlp_in = [scalar_in 128 | inv 224]
#define PH   136   // hb   (bf16) silu hidden 128
#define PD   232   // dotb (bf16) dot 224
#define PAB  484   // aout (bf16) mlp_out 480
#define PIF  132   // inner(f32)  128

// LDS arena (bytes), overlaid live ranges:
//   fin  S1->S2   aout  S5->S6   (region A)
//   scb  S1->S4   inner S5->S6   (region B)
#define OFF_FIN   0        // 16*488*2 = 15616  (aout: 16*484*2 = 15488)
#define OFF_AOUT  0
#define OFF_SCB   15616    // 16*360*2 = 11520  (inner: 16*132*4 = 8448)
#define OFF_INNER 15616
#define OFF_DOTB  27136    // 16*232*2 = 7424   (S2 -> S5)
#define OFF_HB    34560    // 16*136*2 = 4352   (S4 -> S5)
#define OFF_BCOM  38912    // 864*2    = 1728   (bf16 biases)
#define ARENA_SZ  40640

// packed-weight bases (elements) in d_ws (always bf16 after pack)
#define B_UW0 0
#define B_UW1 16384
#define B_UW2 20480
#define B_VW0 21504
#define B_VW1 37888
#define B_VW2 41984
#define B_DW  43008
#define B_W1  71680
#define B_W2  116736
#define PACK_TOT 178176

__device__ inline float bf2f(u16 u) {
    union { uint32_t i; float f; } v; v.i = (uint32_t)u << 16; return v.f;
}
__device__ inline u16 f2bf(float f) {  // round-to-nearest-even
    union { float f; uint32_t i; } v; v.f = f;
    return (u16)((v.i + 0x7fffu + ((v.i >> 16) & 1u)) >> 16);
}
__device__ inline float wsum32(float v) {
    #pragma unroll
    for (int m = 16; m >= 1; m >>= 1) v += __shfl_xor(v, m);
    return v;
}
__device__ inline bool detect_f32(const void* xs) {
    const u16 v = ((const u16*)xs)[threadIdx.x & 63];
    const float f = bf2f(v);
    return __any(!(fabsf(f) < 1e10f)) != 0;
}
__device__ inline float ldin(const void* p, size_t i, bool f32) {
    return f32 ? ((const float*)p)[i] : bf2f(((const u16*)p)[i]);
}
__device__ inline void stout(void* p, size_t i, float v, bool f32) {
    if (f32) ((float*)p)[i] = v; else ((u16*)p)[i] = f2bf(v);
}

struct Ptrs {
    const void *xs, *xp, *lng, *lnb, *o3w, *o3b;
    const void *Uw0, *Uw1, *Uw2, *Ub0, *Vw0, *Vw1, *Vw2, *Vb0;
    const void *dw, *w1, *b1, *w2, *b2;
    const u16 *ws;
    void *out;
};

// Raw accumulate of one 16x16 tile, K = KS*32. Returns unscaled acc.
template<int KS, bool PACKED>
__device__ inline f32x4 mm_acc(const u16* A, int pitchA, const void* W, int D,
                               int tile, int lane, bool wf32)
{
    f32x4 acc = {0.f, 0.f, 0.f, 0.f};
    const int r = lane & 15, g = lane >> 4;
    const u16* arow = A + r * pitchA + g * 8;
    #pragma unroll
    for (int ks = 0; ks < KS; ++ks) {
        s16x8 a = *(const s16x8*)(arow + ks * 32);
        s16x8 b;
        if (PACKED) {
            b = *(const s16x8*)((const u16*)W + (((size_t)tile * KS + ks) * 64 + (size_t)lane) * 8);
        } else {
            union { u16 u[8]; s16x8 v; } bb;
            const int k0 = ks * 32 + g * 8, o = tile * 16 + r;
            #pragma unroll
            for (int j = 0; j < 8; ++j) {
                const size_t idx = (size_t)(k0 + j) * D + o;
                bb.u[j] = wf32 ? f2bf(((const float*)W)[idx]) : ((const u16*)W)[idx];
            }
            b = bb.v;
        }
        acc = __builtin_amdgcn_mfma_f32_16x16x32_bf16(a, b, acc, 0, 0, 0);
    }
    return acc;
}

// Tile + epilogue. TYPE 0: bf16 out = acc*scale + bias  TYPE 1: bf16 out = silu(acc+bias)
// TYPE 2: f32 out = acc
template<int KS, bool PACKED, int TYPE>
__device__ inline void mm_tile(const u16* A, int pitchA, const void* W, int D,
                               int tile, int lane, float scale, const u16* bias,
                               void* outP, int outPitch, bool wf32)
{
    f32x4 acc = mm_acc<KS, PACKED>(A, pitchA, W, D, tile, lane, wf32);
    const int r = lane & 15, g = lane >> 4;
    const int o = tile * 16 + r;
    if (TYPE == 0) {
        const float bv = bias ? bf2f(bias[o]) : 0.f;
        #pragma unroll
        for (int q = 0; q < 4; ++q)
            ((u16*)outP)[(size_t)(g * 4 + q) * outPitch + o] = f2bf(acc[q] * scale + bv);
    } else if (TYPE == 1) {
        const float bv = bf2f(bias[o]);
        #pragma unroll
        for (int q = 0; q < 4; ++q) {
            float x = acc[q] + bv;
            ((u16*)outP)[(size_t)(g * 4 + q) * outPitch + o] = f2bf(x / (1.f + expf(-x)));
        }
    } else {
        #pragma unroll
        for (int q = 0; q < 4; ++q)
            ((float*)outP)[(size_t)(g * 4 + q) * outPitch + o] = acc[q];
    }
}

__global__ void pack_weights(Ptrs P, u16* ws)
{
    const bool wf32 = detect_f32(P.xs);
    const int gid = blockIdx.x * 256 + threadIdx.x;
    if (gid >= PACK_TOT) return;
    const int  base[10] = {B_UW0, B_UW1, B_UW2, B_VW0, B_VW1, B_VW2, B_DW, B_W1, B_W2, PACK_TOT};
    const int  Kd[9]    = {128, 64, 32, 128, 64, 32, 224, 352, 128};
    const void* srcs[9] = {P.Uw0, P.Uw1, P.Uw2, P.Vw0, P.Vw1, P.Vw2, P.dw, P.w1, P.w2};
    const int  Dstride[9] = {128, 64, 32, 128, 64, 32, 128, 128, 480};
    int m = 0;
    for (int i = 1; i < 9; ++i) if (gid >= base[i]) m = i;
    const int e = gid - base[m];
    const int j = e & 7, lane = (e >> 3) & 63, tk = e >> 9;
    const int Ks = Kd[m] >> 5;
    const int ks = tk % Ks, tile = tk / Ks;
    const int k = ks * 32 + ((lane >> 4) << 3) + j;
    const int o = tile * 16 + (lane & 15);
    const size_t idx = (size_t)k * Dstride[m] + o;
    ws[gid] = wf32 ? f2bf(((const float*)srcs[m])[idx]) : ((const u16*)srcs[m])[idx];
}

// ---------------- stage 1: scalar LN + O3 layernorm (one row per half-wave) ----------------
template<int DT>
__device__ inline void stage1_core(const Ptrs& P, u16* fin, u16* scb, int tid, int row0)
{
    const int rr = tid >> 5, l32 = tid & 31;
    const size_t row = (size_t)(row0 + rr);
    const u16*   xsb = (const u16*)P.xs + row * 128;
    const float* xsf = (const float*)P.xs + row * 128;
    const u16*   xpb = (const u16*)P.xp + row * 480;
    const float* xpf = (const float*)P.xp + row * 480;
    {   // scalar layernorm -> scb[rr][0..127]
        float v[4];
        if (DT) { f32x4 u = *(const f32x4*)(xsf + l32 * 4); v[0]=u[0];v[1]=u[1];v[2]=u[2];v[3]=u[3]; }
        else    { u16x4 u = *(const u16x4*)(xsb + l32 * 4);
                  v[0]=bf2f(u[0]);v[1]=bf2f(u[1]);v[2]=bf2f(u[2]);v[3]=bf2f(u[3]); }
        float s  = v[0] + v[1] + v[2] + v[3];
        float s2 = v[0]*v[0] + v[1]*v[1] + v[2]*v[2] + v[3]*v[3];
        s = wsum32(s); s2 = wsum32(s2);
        const float mu = s * (1.f / 128.f);
        const float rs = 1.f / sqrtf(s2 * (1.f / 128.f) - mu * mu + 1e-5f);
        const int c = l32 * 4;
        #pragma unroll
        for (int j2 = 0; j2 < 4; ++j2)
            scb[rr * PS + c + j2] =
                f2bf((v[j2] - mu) * rs * ldin(P.lng, c + j2, DT) + ldin(P.lnb, c + j2, DT));
    }
    {   // s0 O3-LN -> fin[rr][0..127]
        float v[4];
        if (DT) { f32x4 u = *(const f32x4*)(xpf + l32 * 4); v[0]=u[0];v[1]=u[1];v[2]=u[2];v[3]=u[3]; }
        else    { u16x4 u = *(const u16x4*)(xpb + l32 * 4);
                  v[0]=bf2f(u[0]);v[1]=bf2f(u[1]);v[2]=bf2f(u[2]);v[3]=bf2f(u[3]); }
        float s  = v[0] + v[1] + v[2] + v[3];
        float s2 = v[0]*v[0] + v[1]*v[1] + v[2]*v[2] + v[3]*v[3];
        s = wsum32(s); s2 = wsum32(s2);
        const float mu = s * (1.f / 128.f);
        const float rs = 1.f / sqrtf(s2 * (1.f / 128.f) - mu * mu + 1e-5f);
        const int c = l32 * 4;
        #pragma unroll
        for (int j2 = 0; j2 < 4; ++j2)
            fin[rr * PF + c + j2] =
                f2bf((v[j2] - mu) * rs * ldin(P.o3w, c + j2, DT) + ldin(P.o3b, c + j2, DT));
    }
    {   // s1 (64 irreps x 3) -> fin[rr][128 + k*64 + i]
        const int cb = l32 * 6;
        float w[6];
        if (DT) {
            f32x2 a0 = *(const f32x2*)(xpf + 128 + cb);
            f32x2 a1 = *(const f32x2*)(xpf + 128 + cb + 2);
            f32x2 a2 = *(const f32x2*)(xpf + 128 + cb + 4);
            w[0]=a0[0]; w[1]=a0[1]; w[2]=a1[0]; w[3]=a1[1]; w[4]=a2[0]; w[5]=a2[1];
        } else {
            u16x2 a0 = *(const u16x2*)(xpb + 128 + cb);
            u16x2 a1 = *(const u16x2*)(xpb + 128 + cb + 2);
            u16x2 a2 = *(const u16x2*)(xpb + 128 + cb + 4);
            w[0]=bf2f(a0[0]); w[1]=bf2f(a0[1]); w[2]=bf2f(a1[0]);
            w[3]=bf2f(a1[1]); w[4]=bf2f(a2[0]); w[5]=bf2f(a2[1]);
        }
        float ss = 0.f;
        #pragma unroll
        for (int j2 = 0; j2 < 6; ++j2) ss += w[j2] * w[j2];
        ss = wsum32(ss);
        const float rs = 1.f / sqrtf(ss * (1.f / 192.f) + 1e-5f);
        #pragma unroll
        for (int j2 = 0; j2 < 6; ++j2) {
            const int c = cb + j2, i = c / 3, k = c - 3 * i;
            fin[rr * PF + 128 + k * 64 + i] = f2bf(w[j2] * rs * ldin(P.o3w, 128 + i, DT));
        }
    }
    {   // s2 (32 irreps x 5) -> fin[rr][320 + k*32 + i]
        const int cb = l32 * 5;
        float w[5];
        #pragma unroll
        for (int j2 = 0; j2 < 5; ++j2)
            w[j2] = DT ? xpf[320 + cb + j2] : bf2f(xpb[320 + cb + j2]);
        float ss = 0.f;
        #pragma unroll
        for (int j2 = 0; j2 < 5; ++j2) ss += w[j2] * w[j2];
        ss = wsum32(ss);
        const float rs = 1.f / sqrtf(ss * (1.f / 160.f) + 1e-5f);
        #pragma unroll
        for (int j2 = 0; j2 < 5; ++j2) {
            const int c = cb + j2, i = c / 5, k = c - 5 * i;
            fin[rr * PF + 320 + k * 32 + i] = f2bf(w[j2] * rs * ldin(P.o3w, 192 + i, DT));
        }
    }
}

template<bool PACKED>
__global__ __launch_bounds__(NTHR, 6) void xpainn_main(Ptrs P)
{
    __shared__ __align__(16) unsigned char arena[ARENA_SZ];
    u16*   fin    = (u16*)(arena + OFF_FIN);
    u16*   aoutB  = (u16*)(arena + OFF_AOUT);
    u16*   scb    = (u16*)(arena + OFF_SCB);
    float* innerF = (float*)(arena + OFF_INNER);
    u16*   dotb   = (u16*)(arena + OFF_DOTB);
    u16*   hb     = (u16*)(arena + OFF_HB);
    u16*   bcom   = (u16*)(arena + OFF_BCOM);   // bf16 [Ub0 | Vb0 | b1 | b2(480)]

    const int tid = threadIdx.x;
    const int lane = tid & 63, wave = tid >> 6;
    const int r = lane & 15, g = lane >> 4;
    const int row0 = blockIdx.x * RPB;
    const bool isf32 = detect_f32(P.xs);

    // biases -> LDS bf16
    for (int i = tid; i < 864; i += NTHR) {
        const void* src; int off;
        if (i < 128)      { src = P.Ub0; off = i; }
        else if (i < 256) { src = P.Vb0; off = i - 128; }
        else if (i < 384) { src = P.b1;  off = i - 256; }
        else              { src = P.b2;  off = i - 384; }
        bcom[i] = f2bf(ldin(src, off, isf32));
    }
    if (isf32) stage1_core<1>(P, fin, scb, tid, row0);
    else       stage1_core<0>(P, fin, scb, tid, row0);
    __syncthreads();

    // ---------------- S2: U,V O3-linears with in-register inv/dot (S3 fused) ----------------
    // Channel-streamed to keep peak VGPR pressure low (R4 spilled at 64-VGPR cap).
    float u0r[4];          // l0 U, this wave's tile
    float uxr[5][4];       // l1 (3 used) / l2 (5 used) U channels, persistent to S6
    {
        const int o = wave * 16 + r;
        f32x4 au = mm_acc<4, PACKED>(fin, PF,
            PACKED ? (const void*)(P.ws + B_UW0) : P.Uw0, 128, wave, lane, isf32);
        f32x4 av = mm_acc<4, PACKED>(fin, PF,
            PACKED ? (const void*)(P.ws + B_VW0) : P.Vw0, 128, wave, lane, isf32);
        const float bu = bf2f(bcom[o]), bv = bf2f(bcom[128 + o]);
        #pragma unroll
        for (int q = 0; q < 4; ++q) {
            const float U = au[q] * 0.08838834764831845f + bu;
            const float V = av[q] * 0.08838834764831845f + bv;
            u0r[q] = U;
            const int row = g * 4 + q;
            scb[row * PS + 128 + o]  = f2bf(fabsf(V));
            dotb[row * PD + o]       = f2bf(U * V);
        }
    }
    if (wave < 4) {                 // l1: tile tt = wave, 3 channels, K=64
        const int tt = wave, o = tt * 16 + r;
        float sv[4] = {0.f,0.f,0.f,0.f}, suv[4] = {0.f,0.f,0.f,0.f};
        #pragma unroll
        for (int ch = 0; ch < 3; ++ch) {
            f32x4 au = mm_acc<2, PACKED>(fin + 128 + 64 * ch, PF,
                PACKED ? (const void*)(P.ws + B_UW1) : P.Uw1, 64, tt, lane, isf32);
            f32x4 av = mm_acc<2, PACKED>(fin + 128 + 64 * ch, PF,
                PACKED ? (const void*)(P.ws + B_VW1) : P.Vw1, 64, tt, lane, isf32);
            #pragma unroll
            for (int q = 0; q < 4; ++q) {
                const float U = au[q] * 0.125f, V = av[q] * 0.125f;
                uxr[ch][q] = U; sv[q] += V * V; suv[q] += U * V;
            }
        }
        #pragma unroll
        for (int q = 0; q < 4; ++q) {
            const int row = g * 4 + q;
            scb[row * PS + 256 + o]  = f2bf(sqrtf(sv[q]));
            dotb[row * PD + 128 + o] = f2bf(suv[q] * 0.5773502691896258f);
        }
    } else if (wave < 6) {          // l2: tile tt = wave-4, 5 channels, K=32
        const int tt = wave - 4, o = tt * 16 + r;
        float sv[4] = {0.f,0.f,0.f,0.f}, suv[4] = {0.f,0.f,0.f,0.f};
        #pragma unroll
        for (int ch = 0; ch < 5; ++ch) {
            f32x4 au = mm_acc<1, PACKED>(fin + 320 + 32 * ch, PF,
                PACKED ? (const void*)(P.ws + B_UW2) : P.Uw2, 32, tt, lane, isf32);
            f32x4 av = mm_acc<1, PACKED>(fin + 320 + 32 * ch, PF,
                PACKED ? (const void*)(P.ws + B_VW2) : P.Vw2, 32, tt, lane, isf32);
            #pragma unroll
            for (int q = 0; q < 4; ++q) {
                const float U = au[q] * 0.17677669529663687f, V = av[q] * 0.17677669529663687f;
                uxr[ch][q] = U; sv[q] += V * V; suv[q] += U * V;
            }
        }
        #pragma unroll
        for (int q = 0; q < 4; ++q) {
            const int row = g * 4 + q;
            scb[row * PS + 320 + o]  = f2bf(sqrtf(sv[q]));
            dotb[row * PD + 192 + o] = f2bf(suv[q] * 0.4472135954999579f);
        }
    }
    __syncthreads();

    // ---------------- S4: mlp1 + silu -> hb ----------------
    mm_tile<11, PACKED, 1>(scb, PS, PACKED ? (const void*)(P.ws + B_W1) : P.w1,
                           128, wave, lane, 1.f, bcom + 256, hb, PH, isf32);
    __syncthreads();

    // ---------------- S5: mlp2 -> aoutB  AND  inner = dot @ dot_w -> innerF ----------------
    for (int ti = wave; ti < 38; ti += 8) {
        if (ti < 30)
            mm_tile<4, PACKED, 0>(hb, PH, PACKED ? (const void*)(P.ws + B_W2) : P.w2,
                                  480, ti, lane, 1.f, bcom + 384, aoutB, PAB, isf32);
        else
            mm_tile<7, PACKED, 2>(dotb, PD, PACKED ? (const void*)(P.ws + B_DW) : P.dw,
                                  128, ti - 30, lane, 1.f, nullptr, innerF, PIF, isf32);
    }
    __syncthreads();

    // ---------------- S6: outputs ----------------
    // scalar residual, 4-wide: out = xs + a_sv*inner + a_ss   (exactly 1 iter/thread)
    {
        const int idx = tid;               // RPB*32 = 512 == NTHR
        const int r2 = idx >> 5, c4 = (idx & 31) * 4;
        const size_t gb = (size_t)(row0 + r2) * 128 + c4;
        const u16x4 asv = *(const u16x4*)(aoutB + r2 * PAB + 224 + c4);
        const u16x4 ass = *(const u16x4*)(aoutB + r2 * PAB + 352 + c4);
        const f32x4 inn = *(const f32x4*)(innerF + r2 * PIF + c4);
        if (isf32) {
            const f32x4 xs = *(const f32x4*)((const float*)P.xs + gb);
            f32x4 o;
            #pragma unroll
            for (int j = 0; j < 4; ++j) o[j] = xs[j] + bf2f(asv[j]) * inn[j] + bf2f(ass[j]);
            *(f32x4*)((float*)P.out + gb) = o;
        } else {
            const u16x4 xs = *(const u16x4*)((const u16*)P.xs + gb);
            u16x4 o;
            #pragma unroll
            for (int j = 0; j < 4; ++j) o[j] = f2bf(bf2f(xs[j]) + bf2f(asv[j]) * inn[j] + bf2f(ass[j]));
            *(u16x4*)((u16*)P.out + gb) = o;
        }
    }
    // spherical residual from in-register U: out = xp + U * a_vv
    {
        const size_t ob = (size_t)NROWS * 128;
        const int o = wave * 16 + r;     // l0 col
        #pragma unroll
        for (int q = 0; q < 4; ++q) {
            const int row = g * 4 + q;
            const size_t gr = (size_t)(row0 + row) * 480;
            const float av = bf2f(aoutB[row * PAB + o]);
            stout(P.out, ob + gr + o, ldin(P.xp, gr + o, isf32) + u0r[q] * av, isf32);
        }
        if (wave < 4) {
            const int i = wave * 16 + r;
            #pragma unroll
            for (int q = 0; q < 4; ++q) {
                const int row = g * 4 + q;
                const size_t gr = (size_t)(row0 + row) * 480;
                const float av = bf2f(aoutB[row * PAB + 128 + i]);
                #pragma unroll
                for (int ch = 0; ch < 3; ++ch) {
                    const size_t c = 128 + 3 * i + ch;
                    stout(P.out, ob + gr + c, ldin(P.xp, gr + c, isf32) + uxr[ch][q] * av, isf32);
                }
            }
        } else if (wave < 6) {
            const int i = (wave - 4) * 16 + r;
            #pragma unroll
            for (int q = 0; q < 4; ++q) {
                const int row = g * 4 + q;
                const size_t gr = (size_t)(row0 + row) * 480;
                const float av = bf2f(aoutB[row * PAB + 192 + i]);
                #pragma unroll
                for (int ch = 0; ch < 5; ++ch) {
                    const size_t c = 320 + 5 * i + ch;
                    stout(P.out, ob + gr + c, ldin(P.xp, gr + c, isf32) + uxr[ch][q] * av, isf32);
                }
            }
        }
    }
}

extern "C" void kernel_launch(void* const* d_in, const int* in_sizes, int n_in,
                              void* d_out, int out_size, void* d_ws, size_t ws_size,
                              hipStream_t stream)
{
    Ptrs P;
    P.xs  = d_in[0];  P.xp  = d_in[1];
    P.lng = d_in[2];  P.lnb = d_in[3];
    P.o3w = d_in[4];  P.o3b = d_in[5];
    P.Uw0 = d_in[6];  P.Uw1 = d_in[7];
    P.Uw2 = d_in[8];  P.Ub0 = d_in[9];
    P.Vw0 = d_in[10]; P.Vw1 = d_in[11];
    P.Vw2 = d_in[12]; P.Vb0 = d_in[13];
    P.dw  = d_in[14]; P.w1  = d_in[15];
    P.b1  = d_in[16]; P.w2  = d_in[17];
    P.b2  = d_in[18];
    P.ws  = (const u16*)d_ws;
    P.out = d_out;

    const bool packed = (ws_size >= (size_t)PACK_TOT * sizeof(u16));
    if (packed) {
        pack_weights<<<(PACK_TOT + 255) / 256, 256, 0, stream>>>(P, (u16*)d_ws);
        xpainn_main<true><<<NBLK, NTHR, 0, stream>>>(P);
    } else {
        xpainn_main<false><<<NBLK, NTHR, 0, stream>>>(P);
    }
}

// Round 6
// 235.874 us; speedup vs baseline: 3.1163x; 1.0357x over previous
//
#include <hip/hip_runtime.h>
#include <stdint.h>

typedef unsigned short u16;
typedef __attribute__((ext_vector_type(2))) unsigned short u16x2;
typedef __attribute__((ext_vector_type(4))) unsigned short u16x4;
typedef __attribute__((ext_vector_type(8))) short s16x8;   // 8 bf16 (MFMA A/B frag)
typedef __attribute__((ext_vector_type(2))) float f32x2;
typedef __attribute__((ext_vector_type(4))) float f32x4;   // MFMA C/D frag

#define NROWS 100000
#define RPB   32
#define NBLK  (NROWS / RPB)   // 3125 exact
#define NTHR  512

// LDS pitches (elements); per-row-group element strides = 16*pitch
#define PF   488
#define PS   360
#define PH   136
#define PD   232
#define PAB  484
#define PIF  132
#define FIN_RG  (16 * PF)
#define SCB_RG  (16 * PS)
#define HB_RG   (16 * PH)
#define DOT_RG  (16 * PD)
#define AOUT_RG (16 * PAB)
#define INN_RG  (16 * PIF)

// LDS arena (bytes). Overlays: fin(S1-S2)/aout(S5-S6); scb(S1-S4)/inner(S5-S6).
#define OFF_FIN   0        // 2*15616 = 31232  (aout: 2*15488 = 30976)
#define OFF_AOUT  0
#define OFF_SCB   31232    // 2*11520 = 23040  (inner: 2*8448 = 16896)
#define OFF_INNER 31232
#define OFF_DOTB  54272    // 2*7424 = 14848
#define OFF_HB    69120    // 2*4352 = 8704
#define OFF_BCOM  77824    // 864*2  = 1728
#define ARENA_SZ  79552    // <= 81920 -> 2 blocks/CU

// packed-weight bases (elements) in d_ws (bf16 after pack)
#define B_UW0 0
#define B_UW1 16384
#define B_UW2 20480
#define B_VW0 21504
#define B_VW1 37888
#define B_VW2 41984
#define B_DW  43008
#define B_W1  71680
#define B_W2  116736
#define PACK_TOT 178176

__device__ inline float bf2f(u16 u) {
    union { uint32_t i; float f; } v; v.i = (uint32_t)u << 16; return v.f;
}
__device__ inline u16 f2bf(float f) {  // round-to-nearest-even
    union { float f; uint32_t i; } v; v.f = f;
    return (u16)((v.i + 0x7fffu + ((v.i >> 16) & 1u)) >> 16);
}
__device__ inline float wsum32(float v) {
    #pragma unroll
    for (int m = 16; m >= 1; m >>= 1) v += __shfl_xor(v, m);
    return v;
}
__device__ inline bool detect_f32(const void* xs) {
    const u16 v = ((const u16*)xs)[threadIdx.x & 63];
    const float f = bf2f(v);
    return __any(!(fabsf(f) < 1e10f)) != 0;
}
__device__ inline float ldin(const void* p, size_t i, bool f32) {
    return f32 ? ((const float*)p)[i] : bf2f(((const u16*)p)[i]);
}
__device__ inline void stout(void* p, size_t i, float v, bool f32) {
    if (f32) ((float*)p)[i] = v; else ((u16*)p)[i] = f2bf(v);
}

struct Ptrs {
    const void *xs, *xp, *lng, *lnb, *o3w, *o3b;
    const void *Uw0, *Uw1, *Uw2, *Ub0, *Vw0, *Vw1, *Vw2, *Vb0;
    const void *dw, *w1, *b1, *w2, *b2;
    const u16 *ws;
    void *out;
};

// Load KS B-fragments for one 16-col tile into registers (reused across row-groups).
template<int KS, bool PACKED>
__device__ inline void load_b(const void* W, int D, int tile, int lane, bool wf32, s16x8* bfr)
{
    #pragma unroll
    for (int ks = 0; ks < KS; ++ks) {
        if (PACKED) {
            bfr[ks] = *(const s16x8*)((const u16*)W + (((size_t)tile * KS + ks) * 64 + (size_t)lane) * 8);
        } else {
            union { u16 u[8]; s16x8 v; } bb;
            const int k0 = ks * 32 + ((lane >> 4) << 3), o = tile * 16 + (lane & 15);
            #pragma unroll
            for (int j = 0; j < 8; ++j) {
                const size_t idx = (size_t)(k0 + j) * D + o;
                bb.u[j] = wf32 ? f2bf(((const float*)W)[idx]) : ((const u16*)W)[idx];
            }
            bfr[ks] = bb.v;
        }
    }
}

// Accumulate one 16x16 tile from LDS A against pre-loaded B frags.
template<int KS>
__device__ inline f32x4 acc_ab(const u16* A, int pitchA, int lane, const s16x8* bfr)
{
    f32x4 acc = {0.f, 0.f, 0.f, 0.f};
    const u16* arow = A + (lane & 15) * pitchA + (lane >> 4) * 8;
    #pragma unroll
    for (int ks = 0; ks < KS; ++ks) {
        s16x8 a = *(const s16x8*)(arow + ks * 32);
        acc = __builtin_amdgcn_mfma_f32_16x16x32_bf16(a, bfr[ks], acc, 0, 0, 0);
    }
    return acc;
}

// One-shot tile with silu epilogue (used for mlp1; B reloaded per call).
template<int KS, bool PACKED>
__device__ inline void mm_silu(const u16* A, int pitchA, const void* W, int D,
                               int tile, int lane, const u16* bias, u16* outH, bool wf32)
{
    s16x8 bfr[KS];
    load_b<KS, PACKED>(W, D, tile, lane, wf32, bfr);
    f32x4 acc = acc_ab<KS>(A, pitchA, lane, bfr);
    const int r = lane & 15, g = lane >> 4;
    const int o = tile * 16 + r;
    const float bv = bf2f(bias[o]);
    #pragma unroll
    for (int q = 0; q < 4; ++q) {
        float x = acc[q] + bv;
        outH[(g * 4 + q) * PH + o] = f2bf(x / (1.f + expf(-x)));
    }
}

__global__ void pack_weights(Ptrs P, u16* ws)
{
    const bool wf32 = detect_f32(P.xs);
    const int gid = blockIdx.x * 256 + threadIdx.x;
    if (gid >= PACK_TOT) return;
    const int  base[10] = {B_UW0, B_UW1, B_UW2, B_VW0, B_VW1, B_VW2, B_DW, B_W1, B_W2, PACK_TOT};
    const int  Kd[9]    = {128, 64, 32, 128, 64, 32, 224, 352, 128};
    const void* srcs[9] = {P.Uw0, P.Uw1, P.Uw2, P.Vw0, P.Vw1, P.Vw2, P.dw, P.w1, P.w2};
    const int  Dstride[9] = {128, 64, 32, 128, 64, 32, 128, 128, 480};
    int m = 0;
    for (int i = 1; i < 9; ++i) if (gid >= base[i]) m = i;
    const int e = gid - base[m];
    const int j = e & 7, lane = (e >> 3) & 63, tk = e >> 9;
    const int Ks = Kd[m] >> 5;
    const int ks = tk % Ks, tile = tk / Ks;
    const int k = ks * 32 + ((lane >> 4) << 3) + j;
    const int o = tile * 16 + (lane & 15);
    const size_t idx = (size_t)k * Dstride[m] + o;
    ws[gid] = wf32 ? f2bf(((const float*)srcs[m])[idx]) : ((const u16*)srcs[m])[idx];
}

// ---------------- stage 1: LN + O3 layernorm; half-wave handles rows hw, hw+16 ----------------
template<int DT>
__device__ inline void stage1_core(const Ptrs& P, u16* fin0, u16* scb0, int tid, int row0)
{
    const int hw = tid >> 5, l32 = tid & 31;
    #pragma unroll
    for (int rg = 0; rg < 2; ++rg) {
        const int rr = hw + rg * 16;
        const size_t row = (size_t)(row0 + rr);
        u16* finr = fin0 + rg * FIN_RG + hw * PF;
        u16* scbr = scb0 + rg * SCB_RG + hw * PS;
        const u16*   xsb = (const u16*)P.xs + row * 128;
        const float* xsf = (const float*)P.xs + row * 128;
        const u16*   xpb = (const u16*)P.xp + row * 480;
        const float* xpf = (const float*)P.xp + row * 480;
        {   // scalar layernorm -> scbr[0..127]
            float v[4];
            if (DT) { f32x4 u = *(const f32x4*)(xsf + l32 * 4); v[0]=u[0];v[1]=u[1];v[2]=u[2];v[3]=u[3]; }
            else    { u16x4 u = *(const u16x4*)(xsb + l32 * 4);
                      v[0]=bf2f(u[0]);v[1]=bf2f(u[1]);v[2]=bf2f(u[2]);v[3]=bf2f(u[3]); }
            float s  = v[0] + v[1] + v[2] + v[3];
            float s2 = v[0]*v[0] + v[1]*v[1] + v[2]*v[2] + v[3]*v[3];
            s = wsum32(s); s2 = wsum32(s2);
            const float mu = s * (1.f / 128.f);
            const float rs = 1.f / sqrtf(s2 * (1.f / 128.f) - mu * mu + 1e-5f);
            const int c = l32 * 4;
            #pragma unroll
            for (int j2 = 0; j2 < 4; ++j2)
                scbr[c + j2] =
                    f2bf((v[j2] - mu) * rs * ldin(P.lng, c + j2, DT) + ldin(P.lnb, c + j2, DT));
        }
        {   // s0 O3-LN -> finr[0..127]
            float v[4];
            if (DT) { f32x4 u = *(const f32x4*)(xpf + l32 * 4); v[0]=u[0];v[1]=u[1];v[2]=u[2];v[3]=u[3]; }
            else    { u16x4 u = *(const u16x4*)(xpb + l32 * 4);
                      v[0]=bf2f(u[0]);v[1]=bf2f(u[1]);v[2]=bf2f(u[2]);v[3]=bf2f(u[3]); }
            float s  = v[0] + v[1] + v[2] + v[3];
            float s2 = v[0]*v[0] + v[1]*v[1] + v[2]*v[2] + v[3]*v[3];
            s = wsum32(s); s2 = wsum32(s2);
            const float mu = s * (1.f / 128.f);
            const float rs = 1.f / sqrtf(s2 * (1.f / 128.f) - mu * mu + 1e-5f);
            const int c = l32 * 4;
            #pragma unroll
            for (int j2 = 0; j2 < 4; ++j2)
                finr[c + j2] =
                    f2bf((v[j2] - mu) * rs * ldin(P.o3w, c + j2, DT) + ldin(P.o3b, c + j2, DT));
        }
        {   // s1 (64 irreps x 3) -> finr[128 + k*64 + i]
            const int cb = l32 * 6;
            float w[6];
            if (DT) {
                f32x2 a0 = *(const f32x2*)(xpf + 128 + cb);
                f32x2 a1 = *(const f32x2*)(xpf + 128 + cb + 2);
                f32x2 a2 = *(const f32x2*)(xpf + 128 + cb + 4);
                w[0]=a0[0]; w[1]=a0[1]; w[2]=a1[0]; w[3]=a1[1]; w[4]=a2[0]; w[5]=a2[1];
            } else {
                u16x2 a0 = *(const u16x2*)(xpb + 128 + cb);
                u16x2 a1 = *(const u16x2*)(xpb + 128 + cb + 2);
                u16x2 a2 = *(const u16x2*)(xpb + 128 + cb + 4);
                w[0]=bf2f(a0[0]); w[1]=bf2f(a0[1]); w[2]=bf2f(a1[0]);
                w[3]=bf2f(a1[1]); w[4]=bf2f(a2[0]); w[5]=bf2f(a2[1]);
            }
            float ss = 0.f;
            #pragma unroll
            for (int j2 = 0; j2 < 6; ++j2) ss += w[j2] * w[j2];
            ss = wsum32(ss);
            const float rs = 1.f / sqrtf(ss * (1.f / 192.f) + 1e-5f);
            #pragma unroll
            for (int j2 = 0; j2 < 6; ++j2) {
                const int c = cb + j2, i = c / 3, k = c - 3 * i;
                finr[128 + k * 64 + i] = f2bf(w[j2] * rs * ldin(P.o3w, 128 + i, DT));
            }
        }
        {   // s2 (32 irreps x 5) -> finr[320 + k*32 + i]
            const int cb = l32 * 5;
            float w[5];
            #pragma unroll
            for (int j2 = 0; j2 < 5; ++j2)
                w[j2] = DT ? xpf[320 + cb + j2] : bf2f(xpb[320 + cb + j2]);
            float ss = 0.f;
            #pragma unroll
            for (int j2 = 0; j2 < 5; ++j2) ss += w[j2] * w[j2];
            ss = wsum32(ss);
            const float rs = 1.f / sqrtf(ss * (1.f / 160.f) + 1e-5f);
            #pragma unroll
            for (int j2 = 0; j2 < 5; ++j2) {
                const int c = cb + j2, i = c / 5, k = c - 5 * i;
                finr[320 + k * 32 + i] = f2bf(w[j2] * rs * ldin(P.o3w, 192 + i, DT));
            }
        }
    }
}

template<bool PACKED>
__global__ __launch_bounds__(NTHR, 4) void xpainn_main(Ptrs P)
{
    __shared__ __align__(16) unsigned char arena[ARENA_SZ];
    u16*   fin    = (u16*)(arena + OFF_FIN);
    u16*   aoutB  = (u16*)(arena + OFF_AOUT);
    u16*   scb    = (u16*)(arena + OFF_SCB);
    float* innerF = (float*)(arena + OFF_INNER);
    u16*   dotb   = (u16*)(arena + OFF_DOTB);
    u16*   hb     = (u16*)(arena + OFF_HB);
    u16*   bcom   = (u16*)(arena + OFF_BCOM);   // bf16 [Ub0 | Vb0 | b1 | b2(480)]

    const int tid = threadIdx.x;
    const int lane = tid & 63, wave = tid >> 6;
    const int r = lane & 15, g = lane >> 4;
    const int row0 = blockIdx.x * RPB;
    const bool isf32 = detect_f32(P.xs);

    // biases -> LDS bf16
    for (int i = tid; i < 864; i += NTHR) {
        const void* src; int off;
        if (i < 128)      { src = P.Ub0; off = i; }
        else if (i < 256) { src = P.Vb0; off = i - 128; }
        else if (i < 384) { src = P.b1;  off = i - 256; }
        else              { src = P.b2;  off = i - 384; }
        bcom[i] = f2bf(ldin(src, off, isf32));
    }
    if (isf32) stage1_core<1>(P, fin, scb, tid, row0);
    else       stage1_core<0>(P, fin, scb, tid, row0);
    __syncthreads();

    // ---------------- S2: U,V O3-linears, B held in regs across both row-groups ----------------
    float u0r[2][4];       // l0 U (persist to S6)
    float uxr[2][5][4];    // l1 (3 ch) / l2 (5 ch) U (persist to S6)
    {
        s16x8 bU[4], bV[4];
        load_b<4, PACKED>(PACKED ? (const void*)(P.ws + B_UW0) : P.Uw0, 128, wave, lane, isf32, bU);
        load_b<4, PACKED>(PACKED ? (const void*)(P.ws + B_VW0) : P.Vw0, 128, wave, lane, isf32, bV);
        const int o = wave * 16 + r;
        const float bu = bf2f(bcom[o]), bv = bf2f(bcom[128 + o]);
        #pragma unroll
        for (int rg = 0; rg < 2; ++rg) {
            f32x4 au = acc_ab<4>(fin + rg * FIN_RG, PF, lane, bU);
            f32x4 av = acc_ab<4>(fin + rg * FIN_RG, PF, lane, bV);
            u16* scbR = scb + rg * SCB_RG;
            u16* dotR = dotb + rg * DOT_RG;
            #pragma unroll
            for (int q = 0; q < 4; ++q) {
                const float U = au[q] * 0.08838834764831845f + bu;
                const float V = av[q] * 0.08838834764831845f + bv;
                u0r[rg][q] = U;
                const int lrow = g * 4 + q;
                scbR[lrow * PS + 128 + o] = f2bf(fabsf(V));
                dotR[lrow * PD + o]       = f2bf(U * V);
            }
        }
    }
    if (wave < 4) {                 // l1: tile tt = wave, 3 channels, K=64
        const int tt = wave, o = tt * 16 + r;
        float sv[2][4] = {{0.f,0.f,0.f,0.f},{0.f,0.f,0.f,0.f}};
        float suv[2][4] = {{0.f,0.f,0.f,0.f},{0.f,0.f,0.f,0.f}};
        #pragma unroll
        for (int ch = 0; ch < 3; ++ch) {
            s16x8 bU[2], bV[2];
            load_b<2, PACKED>(PACKED ? (const void*)(P.ws + B_UW1) : P.Uw1, 64, tt, lane, isf32, bU);
            load_b<2, PACKED>(PACKED ? (const void*)(P.ws + B_VW1) : P.Vw1, 64, tt, lane, isf32, bV);
            #pragma unroll
            for (int rg = 0; rg < 2; ++rg) {
                f32x4 au = acc_ab<2>(fin + rg * FIN_RG + 128 + 64 * ch, PF, lane, bU);
                f32x4 av = acc_ab<2>(fin + rg * FIN_RG + 128 + 64 * ch, PF, lane, bV);
                #pragma unroll
                for (int q = 0; q < 4; ++q) {
                    const float U = au[q] * 0.125f, V = av[q] * 0.125f;
                    uxr[rg][ch][q] = U; sv[rg][q] += V * V; suv[rg][q] += U * V;
                }
            }
        }
        #pragma unroll
        for (int rg = 0; rg < 2; ++rg) {
            #pragma unroll
            for (int q = 0; q < 4; ++q) {
                const int lrow = g * 4 + q;
                (scb + rg * SCB_RG)[lrow * PS + 256 + o]  = f2bf(sqrtf(sv[rg][q]));
                (dotb + rg * DOT_RG)[lrow * PD + 128 + o] = f2bf(suv[rg][q] * 0.5773502691896258f);
            }
        }
    } else if (wave < 6) {          // l2: tile tt = wave-4, 5 channels, K=32
        const int tt = wave - 4, o = tt * 16 + r;
        float sv[2][4] = {{0.f,0.f,0.f,0.f},{0.f,0.f,0.f,0.f}};
        float suv[2][4] = {{0.f,0.f,0.f,0.f},{0.f,0.f,0.f,0.f}};
        #pragma unroll
        for (int ch = 0; ch < 5; ++ch) {
            s16x8 bU[1], bV[1];
            load_b<1, PACKED>(PACKED ? (const void*)(P.ws + B_UW2) : P.Uw2, 32, tt, lane, isf32, bU);
            load_b<1, PACKED>(PACKED ? (const void*)(P.ws + B_VW2) : P.Vw2, 32, tt, lane, isf32, bV);
            #pragma unroll
            for (int rg = 0; rg < 2; ++rg) {
                f32x4 au = acc_ab<1>(fin + rg * FIN_RG + 320 + 32 * ch, PF, lane, bU);
                f32x4 av = acc_ab<1>(fin + rg * FIN_RG + 320 + 32 * ch, PF, lane, bV);
                #pragma unroll
                for (int q = 0; q < 4; ++q) {
                    const float U = au[q] * 0.17677669529663687f, V = av[q] * 0.17677669529663687f;
                    uxr[rg][ch][q] = U; sv[rg][q] += V * V; suv[rg][q] += U * V;
                }
            }
        }
        #pragma unroll
        for (int rg = 0; rg < 2; ++rg) {
            #pragma unroll
            for (int q = 0; q < 4; ++q) {
                const int lrow = g * 4 + q;
                (scb + rg * SCB_RG)[lrow * PS + 320 + o]  = f2bf(sqrtf(sv[rg][q]));
                (dotb + rg * DOT_RG)[lrow * PD + 192 + o] = f2bf(suv[rg][q] * 0.4472135954999579f);
            }
        }
    }
    __syncthreads();

    // ---------------- S4: mlp1 + silu (KS=11: B reloaded per row-group) ----------------
    #pragma unroll
    for (int rg = 0; rg < 2; ++rg)
        mm_silu<11, PACKED>(scb + rg * SCB_RG, PS, PACKED ? (const void*)(P.ws + B_W1) : P.w1,
                            128, wave, lane, bcom + 256, hb + rg * HB_RG, isf32);
    __syncthreads();

    // ---------------- S5: mlp2 -> aoutB AND inner -> innerF (B held across rgs) ----------------
    for (int ti = wave; ti < 38; ti += 8) {
        if (ti < 30) {
            s16x8 bfr[4];
            load_b<4, PACKED>(PACKED ? (const void*)(P.ws + B_W2) : P.w2, 480, ti, lane, isf32, bfr);
            const int o = ti * 16 + r;
            const float bv = bf2f(bcom[384 + o]);
            #pragma unroll
            for (int rg = 0; rg < 2; ++rg) {
                f32x4 acc = acc_ab<4>(hb + rg * HB_RG, PH, lane, bfr);
                u16* aoutR = aoutB + rg * AOUT_RG;
                #pragma unroll
                for (int q = 0; q < 4; ++q)
                    aoutR[(g * 4 + q) * PAB + o] = f2bf(acc[q] + bv);
            }
        } else {
            s16x8 bfr[7];
            load_b<7, PACKED>(PACKED ? (const void*)(P.ws + B_DW) : P.dw, 128, ti - 30, lane, isf32, bfr);
            const int o = (ti - 30) * 16 + r;
            #pragma unroll
            for (int rg = 0; rg < 2; ++rg) {
                f32x4 acc = acc_ab<7>(dotb + rg * DOT_RG, PD, lane, bfr);
                float* innR = innerF + rg * INN_RG;
                #pragma unroll
                for (int q = 0; q < 4; ++q)
                    innR[(g * 4 + q) * PIF + o] = acc[q];
            }
        }
    }
    __syncthreads();

    // ---------------- S6: outputs ----------------
    // scalar residual, 4-wide, 2 iters/thread
    #pragma unroll
    for (int it = 0; it < 2; ++it) {
        const int idx = tid + it * NTHR;            // 0..1023 = 32 rows x 32 groups
        const int r2 = idx >> 5, c4 = (idx & 31) * 4;
        const u16*  aoutR = aoutB + (r2 >> 4) * AOUT_RG + (r2 & 15) * PAB;
        const float* innR = innerF + (r2 >> 4) * INN_RG + (r2 & 15) * PIF;
        const size_t gb = (size_t)(row0 + r2) * 128 + c4;
        const u16x4 asv = *(const u16x4*)(aoutR + 224 + c4);
        const u16x4 ass = *(const u16x4*)(aoutR + 352 + c4);
        const f32x4 inn = *(const f32x4*)(innR + c4);
        if (isf32) {
            const f32x4 xs = *(const f32x4*)((const float*)P.xs + gb);
            f32x4 o;
            #pragma unroll
            for (int j = 0; j < 4; ++j) o[j] = xs[j] + bf2f(asv[j]) * inn[j] + bf2f(ass[j]);
            *(f32x4*)((float*)P.out + gb) = o;
        } else {
            const u16x4 xs = *(const u16x4*)((const u16*)P.xs + gb);
            u16x4 o;
            #pragma unroll
            for (int j = 0; j < 4; ++j) o[j] = f2bf(bf2f(xs[j]) + bf2f(asv[j]) * inn[j] + bf2f(ass[j]));
            *(u16x4*)((u16*)P.out + gb) = o;
        }
    }
    // spherical residual from in-register U: out = xp + U * a_vv
    {
        const size_t ob = (size_t)NROWS * 128;
        #pragma unroll
        for (int rg = 0; rg < 2; ++rg) {
            const u16* aoutR = aoutB + rg * AOUT_RG;
            const int o = wave * 16 + r;
            #pragma unroll
            for (int q = 0; q < 4; ++q) {
                const int lrow = g * 4 + q;
                const size_t gr = (size_t)(row0 + rg * 16 + lrow) * 480;
                const float av = bf2f(aoutR[lrow * PAB + o]);
                stout(P.out, ob + gr + o, ldin(P.xp, gr + o, isf32) + u0r[rg][q] * av, isf32);
            }
            if (wave < 4) {
                const int i = wave * 16 + r;
                #pragma unroll
                for (int q = 0; q < 4; ++q) {
                    const int lrow = g * 4 + q;
                    const size_t gr = (size_t)(row0 + rg * 16 + lrow) * 480;
                    const float av = bf2f(aoutR[lrow * PAB + 128 + i]);
                    #pragma unroll
                    for (int ch = 0; ch < 3; ++ch) {
                        const size_t c = 128 + 3 * i + ch;
                        stout(P.out, ob + gr + c, ldin(P.xp, gr + c, isf32) + uxr[rg][ch][q] * av, isf32);
                    }
                }
            } else if (wave < 6) {
                const int i = (wave - 4) * 16 + r;
                #pragma unroll
                for (int q = 0; q < 4; ++q) {
                    const int lrow = g * 4 + q;
                    const size_t gr = (size_t)(row0 + rg * 16 + lrow) * 480;
                    const float av = bf2f(aoutR[lrow * PAB + 192 + i]);
                    #pragma unroll
                    for (int ch = 0; ch < 5; ++ch) {
                        const size_t c = 320 + 5 * i + ch;
                        stout(P.out, ob + gr + c, ldin(P.xp, gr + c, isf32) + uxr[rg][ch][q] * av, isf32);
                    }
                }
            }
        }
    }
}

extern "C" void kernel_launch(void* const* d_in, const int* in_sizes, int n_in,
                              void* d_out, int out_size, void* d_ws, size_t ws_size,
                              hipStream_t stream)
{
    Ptrs P;
    P.xs  = d_in[0];  P.xp  = d_in[1];
    P.lng = d_in[2];  P.lnb = d_in[3];
    P.o3w = d_in[4];  P.o3b = d_in[5];
    P.Uw0 = d_in[6];  P.Uw1 = d_in[7];
    P.Uw2 = d_in[8];  P.Ub0 = d_in[9];
    P.Vw0 = d_in[10]; P.Vw1 = d_in[11];
    P.Vw2 = d_in[12]; P.Vb0 = d_in[13];
    P.dw  = d_in[14]; P.w1  = d_in[15];
    P.b1  = d_in[16]; P.w2  = d_in[17];
    P.b2  = d_in[18];
    P.ws  = (const u16*)d_ws;
    P.out = d_out;

    const bool packed = (ws_size >= (size_t)PACK_TOT * sizeof(u16));
    if (packed) {
        pack_weights<<<(PACK_TOT + 255) / 256, 256, 0, stream>>>(P, (u16*)d_ws);
        xpainn_main<true><<<NBLK, NTHR, 0, stream>>>(P);
    } else {
        xpainn_main<false><<<NBLK, NTHR, 0, stream>>>(P);
    }
}